// Round 9
// baseline (464.198 us; speedup 1.0000x reference)
//
#include <hip/hip_runtime.h>
#include <hip/hip_fp16.h>

#define B_SZ  512
#define S_LEN 512
#define D_IN  64
#define H_DIM 32

typedef _Float16 h2 __attribute__((ext_vector_type(2)));

__device__ __forceinline__ float fsig(float x) {
    float e = __builtin_amdgcn_exp2f(x * -1.44269504088896340736f);
    return __builtin_amdgcn_rcpf(1.0f + e);
}
__device__ __forceinline__ float ftanh(float x) {
    float e = __builtin_amdgcn_exp2f(x * -2.88539008177792681472f);
    return __builtin_fmaf(2.0f, __builtin_amdgcn_rcpf(1.0f + e), -1.0f);
}

#if __has_builtin(__builtin_amdgcn_fdot2)
__device__ __forceinline__ float fdot2(h2 a, h2 b, float c) {
    return __builtin_amdgcn_fdot2(a, b, c, false);   // v_dot2_f32_f16
}
#else
__device__ __forceinline__ float fdot2(h2 a, h2 b, float c) {
    return __builtin_fmaf((float)a[1], (float)b[1],
           __builtin_fmaf((float)a[0], (float)b[0], c));
}
#endif

__device__ __forceinline__ h2 u2h2(unsigned int u) { return __builtin_bit_cast(h2, u); }
__device__ __forceinline__ unsigned int pk16(float x, float y) {
    unsigned int lo = __half_as_ushort(__float2half_rn(x));
    unsigned int hi = __half_as_ushort(__float2half_rn(y));
    return lo | (hi << 16);
}

// R6's PROVEN cross-half exchange (ds_bpermute path). permlane32_swap burned
// R7+R8 with unmodellable semantics -- retired.
__device__ __forceinline__ void both_halves(float x, bool lo, float& lorep, float& hirep) {
    float o = __shfl_xor(x, 32);
    lorep = lo ? x : o;
    hirep = lo ? o : x;
}

// Compiler-only memory fence (no instruction, doesn't drain vmcnt); DS ops
// are in-order per wave. Correctness-critical around h broadcasts (R4).
#define LDS_ORDER() asm volatile("" ::: "memory")

// ---------------------------------------------------------------------------
// Kernel 1: gx[row][n] = sum_k x[row][k]*Wih0[n][k] + bih0[n] + bhh0[n]
// Output fp16 u32 lane layout: gxu[row*64 + l] packs for lane l = (gp,j):
//   gp=0 (l<32):  lo = col j      (i),  hi = col 32+j (f)
//   gp=1 (l>=32): lo = col 64+j   (g),  hi = col 96+j (o)
// ---------------------------------------------------------------------------
__global__ __launch_bounds__(256) void xproj_kernel(
    const float* __restrict__ x,
    const float* __restrict__ Wih0,
    const float* __restrict__ bih0,
    const float* __restrict__ bhh0,
    unsigned int* __restrict__ gxu)
{
    __shared__ float xs[64][66];
    __shared__ float wt[64][132];   // Wih0 transposed: wt[k][n]

    const int tid = threadIdx.x;
    const size_t row0 = (size_t)blockIdx.x * 64;

    #pragma unroll
    for (int i = 0; i < 8; ++i) {
        int f4 = tid + i * 256;
        int n  = f4 >> 4;
        int k4 = (f4 & 15) << 2;
        float4 v = reinterpret_cast<const float4*>(Wih0)[f4];
        wt[k4 + 0][n] = v.x;
        wt[k4 + 1][n] = v.y;
        wt[k4 + 2][n] = v.z;
        wt[k4 + 3][n] = v.w;
    }
    #pragma unroll
    for (int i = 0; i < 4; ++i) {
        int f4 = tid + i * 256;
        int r  = f4 >> 4;
        int k4 = (f4 & 15) << 2;
        float4 v = reinterpret_cast<const float4*>(x + row0 * D_IN)[f4];
        xs[r][k4 + 0] = v.x;
        xs[r][k4 + 1] = v.y;
        xs[r][k4 + 2] = v.z;
        xs[r][k4 + 3] = v.w;
    }
    __syncthreads();

    const int cg = tid & 15;
    const int rg = tid >> 4;
    const int j0 = cg << 1;     // j0, j0+1
    const int r0 = rg << 2;

    // acc[r][g*2+q] -> col g*32 + j0 + q
    float acc[4][8];
    #pragma unroll
    for (int g = 0; g < 4; ++g)
        #pragma unroll
        for (int q = 0; q < 2; ++q) {
            int col = g * 32 + j0 + q;
            float bb = bih0[col] + bhh0[col];
            #pragma unroll
            for (int r = 0; r < 4; ++r) acc[r][g * 2 + q] = bb;
        }

    #pragma unroll 4
    for (int k = 0; k < 64; ++k) {
        float wv[8];
        #pragma unroll
        for (int g = 0; g < 4; ++g) {
            float2 w = *reinterpret_cast<const float2*>(&wt[k][g * 32 + j0]);
            wv[2 * g + 0] = w.x;
            wv[2 * g + 1] = w.y;
        }
        float xv[4];
        #pragma unroll
        for (int r = 0; r < 4; ++r) xv[r] = xs[r0 + r][k];
        #pragma unroll
        for (int r = 0; r < 4; ++r)
            #pragma unroll
            for (int c = 0; c < 8; ++c)
                acc[r][c] = __builtin_fmaf(xv[r], wv[c], acc[r][c]);
    }

    #pragma unroll
    for (int r = 0; r < 4; ++r) {
        size_t row = row0 + r0 + r;
        uint2 lo, hi;
        lo.x = pk16(acc[r][0], acc[r][2]);      // j0:   (i, f)
        lo.y = pk16(acc[r][1], acc[r][3]);      // j0+1: (i, f)
        hi.x = pk16(acc[r][4], acc[r][6]);      // j0:   (g, o)
        hi.y = pk16(acc[r][5], acc[r][7]);      // j0+1: (g, o)
        *reinterpret_cast<uint2*>(gxu + row * 64 + j0)      = lo;
        *reinterpret_cast<uint2*>(gxu + row * 64 + 32 + j0) = hi;
    }
}

// ---------------------------------------------------------------------------
// Kernel 2: fused 2-layer LSTM scan + FC. ONE WAVE = TWO BATCH ROWS (P,Q),
// phase-interleaved for ILP (single wave/SIMD => row Q's chains fill row P's
// latency stalls). Weights (96 u32 fp16x2, pinned) are SHARED by both rows.
// Per-row logic is EXACTLY R6's passing kernel: phase order [C,A,B,D,E,F],
// shfl_xor gate combine, fenced LDS h-broadcasts, 2-deep gx prefetch.
// ---------------------------------------------------------------------------
__global__ __launch_bounds__(64, 1) void lstm_scan_kernel(
    const unsigned int* __restrict__ gxu,
    const float* __restrict__ Whh0,
    const float* __restrict__ Wih1,
    const float* __restrict__ Whh1,
    const float* __restrict__ bih1,
    const float* __restrict__ bhh1,
    const float* __restrict__ Wfc,
    const float* __restrict__ bfc,
    float* __restrict__ out)
{
    const int lane = threadIdx.x;
    const int j    = lane & 31;
    const int gp   = lane >> 5;
    const bool lo  = (gp == 0);
    const int b    = blockIdx.x;
    const int rowP = 2 * b;
    const int rowQ = 2 * b + 1;
    const int rA   = gp * 64 + j;        // gate 2gp   row
    const int rB   = rA + 32;            // gate 2gp+1 row

    __shared__ unsigned short h0sm[2][32];   // [row][j]
    __shared__ unsigned short h1sm[2][32];

    // shared per-lane weights: 2 gate rows x 3 matrices, packed fp16 in u32
    unsigned int wh0A[16], wh0B[16], wi1A[16], wi1B[16], wh1A[16], wh1B[16];
    #pragma unroll
    for (int k4 = 0; k4 < 8; ++k4) {
        float4 v;
        v = reinterpret_cast<const float4*>(Whh0 + rA * 32)[k4];
        wh0A[2*k4+0] = pk16(v.x, v.y);  wh0A[2*k4+1] = pk16(v.z, v.w);
        v = reinterpret_cast<const float4*>(Whh0 + rB * 32)[k4];
        wh0B[2*k4+0] = pk16(v.x, v.y);  wh0B[2*k4+1] = pk16(v.z, v.w);
        v = reinterpret_cast<const float4*>(Wih1 + rA * 32)[k4];
        wi1A[2*k4+0] = pk16(v.x, v.y);  wi1A[2*k4+1] = pk16(v.z, v.w);
        v = reinterpret_cast<const float4*>(Wih1 + rB * 32)[k4];
        wi1B[2*k4+0] = pk16(v.x, v.y);  wi1B[2*k4+1] = pk16(v.z, v.w);
        v = reinterpret_cast<const float4*>(Whh1 + rA * 32)[k4];
        wh1A[2*k4+0] = pk16(v.x, v.y);  wh1A[2*k4+1] = pk16(v.z, v.w);
        v = reinterpret_cast<const float4*>(Whh1 + rB * 32)[k4];
        wh1B[2*k4+0] = pk16(v.x, v.y);  wh1B[2*k4+1] = pk16(v.z, v.w);
    }
    // PIN: opaque pass-through; results can't be rematerialized -> live in RF.
    #pragma unroll
    for (int k = 0; k < 16; ++k) {
        asm volatile("" : "+v"(wh0A[k]), "+v"(wh0B[k]),
                          "+v"(wi1A[k]), "+v"(wi1B[k]),
                          "+v"(wh1A[k]), "+v"(wh1B[k]));
    }

    const float b1A = bih1[rA] + bhh1[rA];
    const float b1B = bih1[rB] + bhh1[rB];

    // act-A: gp0 -> sigmoid (i), gp1 -> tanh (g). act-B always sigmoid (f,o).
    const float sclA = gp ? -2.88539008177792681472f : -1.44269504088896340736f;
    const float mulA = gp ?  2.0f : 1.0f;
    const float addA = gp ? -1.0f : 0.0f;

    h2 h0pP[16], h1pP[16], h0pQ[16], h1pQ[16];
    #pragma unroll
    for (int k = 0; k < 16; ++k) {
        h0pP[k] = (h2){0, 0}; h1pP[k] = (h2){0, 0};
        h0pQ[k] = (h2){0, 0}; h1pQ[k] = (h2){0, 0};
    }
    float c0P = 0.f, c1P = 0.f, h1lastP = 0.f;
    float c0Q = 0.f, c1Q = 0.f, h1lastQ = 0.f;

    const unsigned int* gptrP = gxu + (size_t)rowP * S_LEN * 64 + lane;
    const unsigned int* gptrQ = gxu + (size_t)rowQ * S_LEN * 64 + lane;
    h2 gfP = u2h2(gptrP[0]);
    h2 gfQ = u2h2(gptrQ[0]);
    float aAP = (float)gfP[0], aBP = (float)gfP[1];   // L0 preacts t=0
    float aAQ = (float)gfQ[0], aBQ = (float)gfQ[1];
    unsigned int gnextP = gptrP[64];                  // g(t+1), in flight
    unsigned int gnextQ = gptrQ[64];

    for (int t = 0; t < S_LEN; ++t) {
        // prefetch g(t+2) for both rows
        const int tn2 = (t + 2 < S_LEN) ? (t + 2) : (S_LEN - 1);
        const unsigned int gn2P = gptrP[(size_t)tn2 * 64];
        const unsigned int gn2Q = gptrQ[(size_t)tn2 * 64];

        // ---- C: L1 recurrent dots (h1p = h1(t-1)), both rows
        float qA0P = b1A, qA1P = 0.f, qB0P = b1B, qB1P = 0.f;
        float qA0Q = b1A, qA1Q = 0.f, qB0Q = b1B, qB1Q = 0.f;
        #pragma unroll
        for (int k = 0; k < 16; k += 2) {
            qA0P = fdot2(h1pP[k],   u2h2(wh1A[k]),   qA0P);
            qA1P = fdot2(h1pP[k+1], u2h2(wh1A[k+1]), qA1P);
            qB0P = fdot2(h1pP[k],   u2h2(wh1B[k]),   qB0P);
            qB1P = fdot2(h1pP[k+1], u2h2(wh1B[k+1]), qB1P);
            qA0Q = fdot2(h1pQ[k],   u2h2(wh1A[k]),   qA0Q);
            qA1Q = fdot2(h1pQ[k+1], u2h2(wh1A[k+1]), qA1Q);
            qB0Q = fdot2(h1pQ[k],   u2h2(wh1B[k]),   qB0Q);
            qB1Q = fdot2(h1pQ[k+1], u2h2(wh1B[k+1]), qB1Q);
        }

        // ---- A: L0 activations + combine + cell + h0, both rows
        float vAP, vAQ;
        { float e = __builtin_amdgcn_exp2f(sclA * aAP);
          vAP = __builtin_fmaf(mulA, __builtin_amdgcn_rcpf(1.0f + e), addA); }
        { float e = __builtin_amdgcn_exp2f(sclA * aAQ);
          vAQ = __builtin_fmaf(mulA, __builtin_amdgcn_rcpf(1.0f + e), addA); }
        const float vBP = fsig(aBP);
        const float vBQ = fsig(aBQ);
        float ivP, gvP, fvP, ovP, ivQ, gvQ, fvQ, ovQ;
        both_halves(vAP, lo, ivP, gvP);
        both_halves(vBP, lo, fvP, ovP);
        both_halves(vAQ, lo, ivQ, gvQ);
        both_halves(vBQ, lo, fvQ, ovQ);
        c0P = __builtin_fmaf(fvP, c0P, ivP * gvP);
        c0Q = __builtin_fmaf(fvQ, c0Q, ivQ * gvQ);
        const float h0P = ovP * ftanh(c0P);
        const float h0Q = ovQ * ftanh(c0Q);

        // ---- B: h0 broadcasts (fenced; unconditional same-value stores)
        LDS_ORDER();
        h0sm[0][j] = (unsigned short)__half_as_ushort(__float2half_rn(h0P));
        h0sm[1][j] = (unsigned short)__half_as_ushort(__float2half_rn(h0Q));
        LDS_ORDER();
        {
            const uint4* hpP = reinterpret_cast<const uint4*>(&h0sm[0][0]);
            const uint4* hpQ = reinterpret_cast<const uint4*>(&h0sm[1][0]);
            uint4 a0 = hpP[0], a1 = hpP[1], a2 = hpP[2], a3 = hpP[3];
            uint4 b0 = hpQ[0], b1_ = hpQ[1], b2 = hpQ[2], b3 = hpQ[3];
            h0pP[ 0]=u2h2(a0.x); h0pP[ 1]=u2h2(a0.y); h0pP[ 2]=u2h2(a0.z); h0pP[ 3]=u2h2(a0.w);
            h0pP[ 4]=u2h2(a1.x); h0pP[ 5]=u2h2(a1.y); h0pP[ 6]=u2h2(a1.z); h0pP[ 7]=u2h2(a1.w);
            h0pP[ 8]=u2h2(a2.x); h0pP[ 9]=u2h2(a2.y); h0pP[10]=u2h2(a2.z); h0pP[11]=u2h2(a2.w);
            h0pP[12]=u2h2(a3.x); h0pP[13]=u2h2(a3.y); h0pP[14]=u2h2(a3.z); h0pP[15]=u2h2(a3.w);
            h0pQ[ 0]=u2h2(b0.x); h0pQ[ 1]=u2h2(b0.y); h0pQ[ 2]=u2h2(b0.z); h0pQ[ 3]=u2h2(b0.w);
            h0pQ[ 4]=u2h2(b1_.x); h0pQ[ 5]=u2h2(b1_.y); h0pQ[ 6]=u2h2(b1_.z); h0pQ[ 7]=u2h2(b1_.w);
            h0pQ[ 8]=u2h2(b2.x); h0pQ[ 9]=u2h2(b2.y); h0pQ[10]=u2h2(b2.z); h0pQ[11]=u2h2(b2.w);
            h0pQ[12]=u2h2(b3.x); h0pQ[13]=u2h2(b3.y); h0pQ[14]=u2h2(b3.z); h0pQ[15]=u2h2(b3.w);
        }

        // ---- D: L1 input dots + next-step L0 dots, both rows
        #pragma unroll
        for (int k = 0; k < 16; k += 2) {
            qA0P = fdot2(h0pP[k],   u2h2(wi1A[k]),   qA0P);
            qA1P = fdot2(h0pP[k+1], u2h2(wi1A[k+1]), qA1P);
            qB0P = fdot2(h0pP[k],   u2h2(wi1B[k]),   qB0P);
            qB1P = fdot2(h0pP[k+1], u2h2(wi1B[k+1]), qB1P);
            qA0Q = fdot2(h0pQ[k],   u2h2(wi1A[k]),   qA0Q);
            qA1Q = fdot2(h0pQ[k+1], u2h2(wi1A[k+1]), qA1Q);
            qB0Q = fdot2(h0pQ[k],   u2h2(wi1B[k]),   qB0Q);
            qB1Q = fdot2(h0pQ[k+1], u2h2(wi1B[k+1]), qB1Q);
        }
        h2 gnpP = u2h2(gnextP);
        h2 gnpQ = u2h2(gnextQ);
        float zA0P = (float)gnpP[0], zA1P = 0.f, zB0P = (float)gnpP[1], zB1P = 0.f;
        float zA0Q = (float)gnpQ[0], zA1Q = 0.f, zB0Q = (float)gnpQ[1], zB1Q = 0.f;
        #pragma unroll
        for (int k = 0; k < 16; k += 2) {
            zA0P = fdot2(h0pP[k],   u2h2(wh0A[k]),   zA0P);
            zA1P = fdot2(h0pP[k+1], u2h2(wh0A[k+1]), zA1P);
            zB0P = fdot2(h0pP[k],   u2h2(wh0B[k]),   zB0P);
            zB1P = fdot2(h0pP[k+1], u2h2(wh0B[k+1]), zB1P);
            zA0Q = fdot2(h0pQ[k],   u2h2(wh0A[k]),   zA0Q);
            zA1Q = fdot2(h0pQ[k+1], u2h2(wh0A[k+1]), zA1Q);
            zB0Q = fdot2(h0pQ[k],   u2h2(wh0B[k]),   zB0Q);
            zB1Q = fdot2(h0pQ[k+1], u2h2(wh0B[k+1]), zB1Q);
        }

        // ---- E: L1 activations + combine + cell + h1, both rows
        const float qAP = qA0P + qA1P, qBP = qB0P + qB1P;
        const float qAQ = qA0Q + qA1Q, qBQ = qB0Q + qB1Q;
        float wAP, wAQ;
        { float e = __builtin_amdgcn_exp2f(sclA * qAP);
          wAP = __builtin_fmaf(mulA, __builtin_amdgcn_rcpf(1.0f + e), addA); }
        { float e = __builtin_amdgcn_exp2f(sclA * qAQ);
          wAQ = __builtin_fmaf(mulA, __builtin_amdgcn_rcpf(1.0f + e), addA); }
        const float wBP = fsig(qBP);
        const float wBQ = fsig(qBQ);
        float iv1P, gv1P, fv1P, ov1P, iv1Q, gv1Q, fv1Q, ov1Q;
        both_halves(wAP, lo, iv1P, gv1P);
        both_halves(wBP, lo, fv1P, ov1P);
        both_halves(wAQ, lo, iv1Q, gv1Q);
        both_halves(wBQ, lo, fv1Q, ov1Q);
        c1P = __builtin_fmaf(fv1P, c1P, iv1P * gv1P);
        c1Q = __builtin_fmaf(fv1Q, c1Q, iv1Q * gv1Q);
        const float h1P = ov1P * ftanh(c1P);
        const float h1Q = ov1Q * ftanh(c1Q);
        h1lastP = h1P;
        h1lastQ = h1Q;

        // ---- F: h1 broadcasts (consumed next iter at C -> hidden)
        LDS_ORDER();
        h1sm[0][j] = (unsigned short)__half_as_ushort(__float2half_rn(h1P));
        h1sm[1][j] = (unsigned short)__half_as_ushort(__float2half_rn(h1Q));
        LDS_ORDER();
        {
            const uint4* hpP = reinterpret_cast<const uint4*>(&h1sm[0][0]);
            const uint4* hpQ = reinterpret_cast<const uint4*>(&h1sm[1][0]);
            uint4 a0 = hpP[0], a1 = hpP[1], a2 = hpP[2], a3 = hpP[3];
            uint4 b0 = hpQ[0], b1_ = hpQ[1], b2 = hpQ[2], b3 = hpQ[3];
            h1pP[ 0]=u2h2(a0.x); h1pP[ 1]=u2h2(a0.y); h1pP[ 2]=u2h2(a0.z); h1pP[ 3]=u2h2(a0.w);
            h1pP[ 4]=u2h2(a1.x); h1pP[ 5]=u2h2(a1.y); h1pP[ 6]=u2h2(a1.z); h1pP[ 7]=u2h2(a1.w);
            h1pP[ 8]=u2h2(a2.x); h1pP[ 9]=u2h2(a2.y); h1pP[10]=u2h2(a2.z); h1pP[11]=u2h2(a2.w);
            h1pP[12]=u2h2(a3.x); h1pP[13]=u2h2(a3.y); h1pP[14]=u2h2(a3.z); h1pP[15]=u2h2(a3.w);
            h1pQ[ 0]=u2h2(b0.x); h1pQ[ 1]=u2h2(b0.y); h1pQ[ 2]=u2h2(b0.z); h1pQ[ 3]=u2h2(b0.w);
            h1pQ[ 4]=u2h2(b1_.x); h1pQ[ 5]=u2h2(b1_.y); h1pQ[ 6]=u2h2(b1_.z); h1pQ[ 7]=u2h2(b1_.w);
            h1pQ[ 8]=u2h2(b2.x); h1pQ[ 9]=u2h2(b2.y); h1pQ[10]=u2h2(b2.z); h1pQ[11]=u2h2(b2.w);
            h1pQ[12]=u2h2(b3.x); h1pQ[13]=u2h2(b3.y); h1pQ[14]=u2h2(b3.z); h1pQ[15]=u2h2(b3.w);
        }

        aAP = (zA0P + zA1P);  aBP = (zB0P + zB1P);
        aAQ = (zA0Q + zA1Q);  aBQ = (zB0Q + zB1Q);
        gnextP = gn2P;
        gnextQ = gn2Q;
    }

    // ---- FC epilogue (both rows): lanes hold h1(j) duplicated across halves
    float pP = h1lastP * Wfc[j];
    float pQ = h1lastQ * Wfc[j];
    #pragma unroll
    for (int s = 16; s >= 1; s >>= 1) {
        pP += __shfl_xor(pP, s);
        pQ += __shfl_xor(pQ, s);
    }
    if (lane == 0) {
        out[rowP] = pP + bfc[0];
        out[rowQ] = pQ + bfc[0];
    }
}

extern "C" void kernel_launch(void* const* d_in, const int* in_sizes, int n_in,
                              void* d_out, int out_size, void* d_ws, size_t ws_size,
                              hipStream_t stream) {
    (void)in_sizes; (void)n_in; (void)out_size;
    const float* x    = (const float*)d_in[0];
    const float* Wih0 = (const float*)d_in[1];
    const float* Whh0 = (const float*)d_in[2];
    const float* bih0 = (const float*)d_in[3];
    const float* bhh0 = (const float*)d_in[4];
    const float* Wih1 = (const float*)d_in[5];
    const float* Whh1 = (const float*)d_in[6];
    const float* bih1 = (const float*)d_in[7];
    const float* bhh1 = (const float*)d_in[8];
    const float* Wfc  = (const float*)d_in[9];
    const float* bfc  = (const float*)d_in[10];
    float* out = (float*)d_out;

    const size_t need = (size_t)B_SZ * S_LEN * 64 * sizeof(unsigned int);  // 64 MB
    if (ws_size < need) return;
    unsigned int* gxu = (unsigned int*)d_ws;

    hipLaunchKernelGGL(xproj_kernel, dim3((B_SZ * S_LEN) / 64), dim3(256), 0, stream,
                       x, Wih0, bih0, bhh0, gxu);
    hipLaunchKernelGGL(lstm_scan_kernel, dim3(B_SZ / 2), dim3(64), 0, stream,
                       gxu, Whh0, Wih1, Whh1, bih1, bhh1, Wfc, bfc, out);
}

// Round 10
// 292.976 us; speedup vs baseline: 1.5844x; 1.5844x over previous
//
#include <hip/hip_runtime.h>
#include <hip/hip_fp16.h>

#define B_SZ  512
#define S_LEN 512
#define D_IN  64
#define H_DIM 32

typedef _Float16 h2 __attribute__((ext_vector_type(2)));

__device__ __forceinline__ float fsig(float x) {
    float e = __builtin_amdgcn_exp2f(x * -1.44269504088896340736f);
    return __builtin_amdgcn_rcpf(1.0f + e);
}
__device__ __forceinline__ float ftanh(float x) {
    float e = __builtin_amdgcn_exp2f(x * -2.88539008177792681472f);
    return __builtin_fmaf(2.0f, __builtin_amdgcn_rcpf(1.0f + e), -1.0f);
}

#if __has_builtin(__builtin_amdgcn_fdot2)
__device__ __forceinline__ float fdot2(h2 a, h2 b, float c) {
    return __builtin_amdgcn_fdot2(a, b, c, false);   // v_dot2_f32_f16
}
#else
__device__ __forceinline__ float fdot2(h2 a, h2 b, float c) {
    return __builtin_fmaf((float)a[1], (float)b[1],
           __builtin_fmaf((float)a[0], (float)b[0], c));
}
#endif

__device__ __forceinline__ h2 u2h2(unsigned int u) { return __builtin_bit_cast(h2, u); }
__device__ __forceinline__ unsigned int pk16(float x, float y) {
    unsigned int lo = __half_as_ushort(__float2half_rn(x));
    unsigned int hi = __half_as_ushort(__float2half_rn(y));
    return lo | (hi << 16);
}

// R6's PROVEN cross-half exchange (ds_bpermute path).
__device__ __forceinline__ void both_halves(float x, bool lo, float& lorep, float& hirep) {
    float o = __shfl_xor(x, 32);
    lorep = lo ? x : o;
    hirep = lo ? o : x;
}

// Compiler-only memory fence (no instruction, doesn't drain vmcnt); DS ops
// are in-order per wave. Correctness-critical around h broadcasts (R4).
#define LDS_ORDER() asm volatile("" ::: "memory")

// ---------------------------------------------------------------------------
// Kernel 1: gx[row][n] = sum_k x[row][k]*Wih0[n][k] + bih0[n] + bhh0[n]
// Output fp16 u32 lane layout: gxu[row*64 + l] packs for lane l = (gp,j):
//   gp=0 (l<32):  lo = col j      (i),  hi = col 32+j (f)
//   gp=1 (l>=32): lo = col 64+j   (g),  hi = col 96+j (o)
// ---------------------------------------------------------------------------
__global__ __launch_bounds__(256) void xproj_kernel(
    const float* __restrict__ x,
    const float* __restrict__ Wih0,
    const float* __restrict__ bih0,
    const float* __restrict__ bhh0,
    unsigned int* __restrict__ gxu)
{
    __shared__ float xs[64][66];
    __shared__ float wt[64][132];   // Wih0 transposed: wt[k][n]

    const int tid = threadIdx.x;
    const size_t row0 = (size_t)blockIdx.x * 64;

    #pragma unroll
    for (int i = 0; i < 8; ++i) {
        int f4 = tid + i * 256;
        int n  = f4 >> 4;
        int k4 = (f4 & 15) << 2;
        float4 v = reinterpret_cast<const float4*>(Wih0)[f4];
        wt[k4 + 0][n] = v.x;
        wt[k4 + 1][n] = v.y;
        wt[k4 + 2][n] = v.z;
        wt[k4 + 3][n] = v.w;
    }
    #pragma unroll
    for (int i = 0; i < 4; ++i) {
        int f4 = tid + i * 256;
        int r  = f4 >> 4;
        int k4 = (f4 & 15) << 2;
        float4 v = reinterpret_cast<const float4*>(x + row0 * D_IN)[f4];
        xs[r][k4 + 0] = v.x;
        xs[r][k4 + 1] = v.y;
        xs[r][k4 + 2] = v.z;
        xs[r][k4 + 3] = v.w;
    }
    __syncthreads();

    const int cg = tid & 15;
    const int rg = tid >> 4;
    const int j0 = cg << 1;     // j0, j0+1
    const int r0 = rg << 2;

    // acc[r][g*2+q] -> col g*32 + j0 + q
    float acc[4][8];
    #pragma unroll
    for (int g = 0; g < 4; ++g)
        #pragma unroll
        for (int q = 0; q < 2; ++q) {
            int col = g * 32 + j0 + q;
            float bb = bih0[col] + bhh0[col];
            #pragma unroll
            for (int r = 0; r < 4; ++r) acc[r][g * 2 + q] = bb;
        }

    #pragma unroll 4
    for (int k = 0; k < 64; ++k) {
        float wv[8];
        #pragma unroll
        for (int g = 0; g < 4; ++g) {
            float2 w = *reinterpret_cast<const float2*>(&wt[k][g * 32 + j0]);
            wv[2 * g + 0] = w.x;
            wv[2 * g + 1] = w.y;
        }
        float xv[4];
        #pragma unroll
        for (int r = 0; r < 4; ++r) xv[r] = xs[r0 + r][k];
        #pragma unroll
        for (int r = 0; r < 4; ++r)
            #pragma unroll
            for (int c = 0; c < 8; ++c)
                acc[r][c] = __builtin_fmaf(xv[r], wv[c], acc[r][c]);
    }

    #pragma unroll
    for (int r = 0; r < 4; ++r) {
        size_t row = row0 + r0 + r;
        uint2 lo, hi;
        lo.x = pk16(acc[r][0], acc[r][2]);      // j0:   (i, f)
        lo.y = pk16(acc[r][1], acc[r][3]);      // j0+1: (i, f)
        hi.x = pk16(acc[r][4], acc[r][6]);      // j0:   (g, o)
        hi.y = pk16(acc[r][5], acc[r][7]);      // j0+1: (g, o)
        *reinterpret_cast<uint2*>(gxu + row * 64 + j0)      = lo;
        *reinterpret_cast<uint2*>(gxu + row * 64 + 32 + j0) = hi;
    }
}

// ---------------------------------------------------------------------------
// Kernel 2: fused 2-layer LSTM scan + FC. ONE WAVE PER BATCH ROW (512 blocks,
// the R6 config that gave 2 waves/CU). LAYER-SKEWED schedule: iteration t
// runs L0-act(step t) and L1-act(step t-1) as INDEPENDENT parallel chains,
// then ONE fenced LDS window broadcasts h0(t) and h1(t-1) together, then all
// dots (L0 for t+1, L1 for t) issue after the single read. Per-row math is
// bit-identical to R6; only the iteration assignment changed.
// Primitives unchanged from R6: shfl_xor(32) combine, fenced unconditional
// LDS stores, pinned weights (96 u32 fp16x2), 2-deep gx prefetch.
// ---------------------------------------------------------------------------
__global__ __launch_bounds__(64, 1) void lstm_scan_kernel(
    const unsigned int* __restrict__ gxu,
    const float* __restrict__ Whh0,
    const float* __restrict__ Wih1,
    const float* __restrict__ Whh1,
    const float* __restrict__ bih1,
    const float* __restrict__ bhh1,
    const float* __restrict__ Wfc,
    const float* __restrict__ bfc,
    float* __restrict__ out)
{
    const int lane = threadIdx.x;
    const int j    = lane & 31;
    const int gp   = lane >> 5;
    const bool lo  = (gp == 0);
    const int b    = blockIdx.x;
    const int rA   = gp * 64 + j;        // gate 2gp   row
    const int rB   = rA + 32;            // gate 2gp+1 row

    __shared__ unsigned short h0sm[32];
    __shared__ unsigned short h1sm[32];

    // per-lane weights: 2 gate rows x 3 matrices, packed fp16 pairs in u32
    unsigned int wh0A[16], wh0B[16], wi1A[16], wi1B[16], wh1A[16], wh1B[16];
    #pragma unroll
    for (int k4 = 0; k4 < 8; ++k4) {
        float4 v;
        v = reinterpret_cast<const float4*>(Whh0 + rA * 32)[k4];
        wh0A[2*k4+0] = pk16(v.x, v.y);  wh0A[2*k4+1] = pk16(v.z, v.w);
        v = reinterpret_cast<const float4*>(Whh0 + rB * 32)[k4];
        wh0B[2*k4+0] = pk16(v.x, v.y);  wh0B[2*k4+1] = pk16(v.z, v.w);
        v = reinterpret_cast<const float4*>(Wih1 + rA * 32)[k4];
        wi1A[2*k4+0] = pk16(v.x, v.y);  wi1A[2*k4+1] = pk16(v.z, v.w);
        v = reinterpret_cast<const float4*>(Wih1 + rB * 32)[k4];
        wi1B[2*k4+0] = pk16(v.x, v.y);  wi1B[2*k4+1] = pk16(v.z, v.w);
        v = reinterpret_cast<const float4*>(Whh1 + rA * 32)[k4];
        wh1A[2*k4+0] = pk16(v.x, v.y);  wh1A[2*k4+1] = pk16(v.z, v.w);
        v = reinterpret_cast<const float4*>(Whh1 + rB * 32)[k4];
        wh1B[2*k4+0] = pk16(v.x, v.y);  wh1B[2*k4+1] = pk16(v.z, v.w);
    }
    // PIN: opaque pass-through; results can't be rematerialized -> stay live.
    #pragma unroll
    for (int k = 0; k < 16; ++k) {
        asm volatile("" : "+v"(wh0A[k]), "+v"(wh0B[k]),
                          "+v"(wi1A[k]), "+v"(wi1B[k]),
                          "+v"(wh1A[k]), "+v"(wh1B[k]));
    }

    const float b1A = bih1[rA] + bhh1[rA];
    const float b1B = bih1[rB] + bhh1[rB];

    // act-A: gp0 -> sigmoid (i), gp1 -> tanh (g). act-B always sigmoid (f,o).
    const float sclA = gp ? -2.88539008177792681472f : -1.44269504088896340736f;
    const float mulA = gp ?  2.0f : 1.0f;
    const float addA = gp ? -1.0f : 0.0f;

    h2 h0p[16], h1p[16];
    #pragma unroll
    for (int k = 0; k < 16; ++k) { h0p[k] = (h2){0, 0}; h1p[k] = (h2){0, 0}; }
    float c0 = 0.f, c1 = 0.f;
    float h1cur = 0.f;                 // h1(t-1); = h1(-1) = 0 at t=0

    const unsigned int* gptr = gxu + (size_t)b * S_LEN * 64 + lane;
    h2 gfirst = u2h2(gptr[0]);
    float aA = (float)gfirst[0];       // L0 preacts for step t (t=0: h0(-1)=0)
    float aB = (float)gfirst[1];
    float qA = 0.f, qB = 0.f;          // L1 preacts for step t-1 (valid t>0)
    unsigned int gnext = gptr[64];     // g(t+1), in flight

    for (int t = 0; t < S_LEN; ++t) {
        // prefetch g(t+2)
        const int tn2 = (t + 2 < S_LEN) ? (t + 2) : (S_LEN - 1);
        const unsigned int gn2 = gptr[(size_t)tn2 * 64];

        // ---- L0 act chain for step t (independent of L1 chain below)
        float vA;
        { float e = __builtin_amdgcn_exp2f(sclA * aA);
          vA = __builtin_fmaf(mulA, __builtin_amdgcn_rcpf(1.0f + e), addA); }
        const float vB = fsig(aB);
        float iv, gv, fv, ov;
        both_halves(vA, lo, iv, gv);
        both_halves(vB, lo, fv, ov);
        c0 = __builtin_fmaf(fv, c0, iv * gv);
        const float h0 = ov * ftanh(c0);

        // ---- L1 act chain for step t-1 (parallel with the L0 chain)
        if (t > 0) {
            float wA;
            { float e = __builtin_amdgcn_exp2f(sclA * qA);
              wA = __builtin_fmaf(mulA, __builtin_amdgcn_rcpf(1.0f + e), addA); }
            const float wB = fsig(qB);
            float iv1, gv1, fv1, ov1;
            both_halves(wA, lo, iv1, gv1);
            both_halves(wB, lo, fv1, ov1);
            c1 = __builtin_fmaf(fv1, c1, iv1 * gv1);
            h1cur = ov1 * ftanh(c1);   // h1(t-1)
        }

        // ---- SINGLE broadcast window: h0(t) and h1(t-1) together
        LDS_ORDER();
        h0sm[j] = (unsigned short)__half_as_ushort(__float2half_rn(h0));
        h1sm[j] = (unsigned short)__half_as_ushort(__float2half_rn(h1cur));
        LDS_ORDER();
        {
            const uint4* hp0 = reinterpret_cast<const uint4*>(h0sm);
            const uint4* hp1 = reinterpret_cast<const uint4*>(h1sm);
            uint4 a0 = hp0[0], a1 = hp0[1], a2 = hp0[2], a3 = hp0[3];
            uint4 d0 = hp1[0], d1 = hp1[1], d2 = hp1[2], d3 = hp1[3];
            h0p[ 0]=u2h2(a0.x); h0p[ 1]=u2h2(a0.y); h0p[ 2]=u2h2(a0.z); h0p[ 3]=u2h2(a0.w);
            h0p[ 4]=u2h2(a1.x); h0p[ 5]=u2h2(a1.y); h0p[ 6]=u2h2(a1.z); h0p[ 7]=u2h2(a1.w);
            h0p[ 8]=u2h2(a2.x); h0p[ 9]=u2h2(a2.y); h0p[10]=u2h2(a2.z); h0p[11]=u2h2(a2.w);
            h0p[12]=u2h2(a3.x); h0p[13]=u2h2(a3.y); h0p[14]=u2h2(a3.z); h0p[15]=u2h2(a3.w);
            h1p[ 0]=u2h2(d0.x); h1p[ 1]=u2h2(d0.y); h1p[ 2]=u2h2(d0.z); h1p[ 3]=u2h2(d0.w);
            h1p[ 4]=u2h2(d1.x); h1p[ 5]=u2h2(d1.y); h1p[ 6]=u2h2(d1.z); h1p[ 7]=u2h2(d1.w);
            h1p[ 8]=u2h2(d2.x); h1p[ 9]=u2h2(d2.y); h1p[10]=u2h2(d2.z); h1p[11]=u2h2(d2.w);
            h1p[12]=u2h2(d3.x); h1p[13]=u2h2(d3.y); h1p[14]=u2h2(d3.z); h1p[15]=u2h2(d3.w);
        }

        // ---- Dots: L0 for step t+1 (gx(t+1) + Whh0.h0(t)) and
        //            L1 for step t   (b1 + Wih1.h0(t) + Whh1.h1(t-1))
        h2 gnp = u2h2(gnext);
        float zA0 = (float)gnp[0], zA1 = 0.f;
        float zB0 = (float)gnp[1], zB1 = 0.f;
        float qA0 = b1A, qA1 = 0.f, qB0 = b1B, qB1 = 0.f;
        #pragma unroll
        for (int k = 0; k < 16; k += 2) {
            zA0 = fdot2(h0p[k],   u2h2(wh0A[k]),   zA0);
            zA1 = fdot2(h0p[k+1], u2h2(wh0A[k+1]), zA1);
            zB0 = fdot2(h0p[k],   u2h2(wh0B[k]),   zB0);
            zB1 = fdot2(h0p[k+1], u2h2(wh0B[k+1]), zB1);
            qA0 = fdot2(h0p[k],   u2h2(wi1A[k]),   qA0);
            qA1 = fdot2(h0p[k+1], u2h2(wi1A[k+1]), qA1);
            qB0 = fdot2(h0p[k],   u2h2(wi1B[k]),   qB0);
            qB1 = fdot2(h0p[k+1], u2h2(wi1B[k+1]), qB1);
        }
        #pragma unroll
        for (int k = 0; k < 16; k += 2) {
            qA0 = fdot2(h1p[k],   u2h2(wh1A[k]),   qA0);
            qA1 = fdot2(h1p[k+1], u2h2(wh1A[k+1]), qA1);
            qB0 = fdot2(h1p[k],   u2h2(wh1B[k]),   qB0);
            qB1 = fdot2(h1p[k+1], u2h2(wh1B[k+1]), qB1);
        }

        aA = zA0 + zA1;  aB = zB0 + zB1;
        qA = qA0 + qA1;  qB = qB0 + qB1;
        gnext = gn2;
    }

    // ---- Epilogue: final L1 act for step S-1
    float h1last;
    {
        float wA;
        { float e = __builtin_amdgcn_exp2f(sclA * qA);
          wA = __builtin_fmaf(mulA, __builtin_amdgcn_rcpf(1.0f + e), addA); }
        const float wB = fsig(qB);
        float iv1, gv1, fv1, ov1;
        both_halves(wA, lo, iv1, gv1);
        both_halves(wB, lo, fv1, ov1);
        c1 = __builtin_fmaf(fv1, c1, iv1 * gv1);
        h1last = ov1 * ftanh(c1);
    }

    // ---- FC epilogue: lanes hold h1(j) (duplicated across halves)
    float p = h1last * Wfc[j];
    p += __shfl_xor(p, 16);
    p += __shfl_xor(p, 8);
    p += __shfl_xor(p, 4);
    p += __shfl_xor(p, 2);
    p += __shfl_xor(p, 1);
    if (lane == 0) out[b] = p + bfc[0];
}

extern "C" void kernel_launch(void* const* d_in, const int* in_sizes, int n_in,
                              void* d_out, int out_size, void* d_ws, size_t ws_size,
                              hipStream_t stream) {
    (void)in_sizes; (void)n_in; (void)out_size;
    const float* x    = (const float*)d_in[0];
    const float* Wih0 = (const float*)d_in[1];
    const float* Whh0 = (const float*)d_in[2];
    const float* bih0 = (const float*)d_in[3];
    const float* bhh0 = (const float*)d_in[4];
    const float* Wih1 = (const float*)d_in[5];
    const float* Whh1 = (const float*)d_in[6];
    const float* bih1 = (const float*)d_in[7];
    const float* bhh1 = (const float*)d_in[8];
    const float* Wfc  = (const float*)d_in[9];
    const float* bfc  = (const float*)d_in[10];
    float* out = (float*)d_out;

    const size_t need = (size_t)B_SZ * S_LEN * 64 * sizeof(unsigned int);  // 64 MB
    if (ws_size < need) return;
    unsigned int* gxu = (unsigned int*)d_ws;

    hipLaunchKernelGGL(xproj_kernel, dim3((B_SZ * S_LEN) / 64), dim3(256), 0, stream,
                       x, Wih0, bih0, bhh0, gxu);
    hipLaunchKernelGGL(lstm_scan_kernel, dim3(B_SZ), dim3(64), 0, stream,
                       gxu, Whh0, Wih1, Whh1, bih1, bhh1, Wfc, bfc, out);
}

// Round 11
// 283.589 us; speedup vs baseline: 1.6369x; 1.0331x over previous
//
#include <hip/hip_runtime.h>
#include <hip/hip_fp16.h>

#define B_SZ  512
#define S_LEN 512
#define D_IN  64
#define H_DIM 32

typedef _Float16 h2 __attribute__((ext_vector_type(2)));

__device__ __forceinline__ float fsig(float x) {
    float e = __builtin_amdgcn_exp2f(x * -1.44269504088896340736f);
    return __builtin_amdgcn_rcpf(1.0f + e);
}
__device__ __forceinline__ float ftanh(float x) {
    float e = __builtin_amdgcn_exp2f(x * -2.88539008177792681472f);
    return __builtin_fmaf(2.0f, __builtin_amdgcn_rcpf(1.0f + e), -1.0f);
}

#if __has_builtin(__builtin_amdgcn_fdot2)
__device__ __forceinline__ float fdot2(h2 a, h2 b, float c) {
    return __builtin_amdgcn_fdot2(a, b, c, false);   // v_dot2_f32_f16
}
#else
__device__ __forceinline__ float fdot2(h2 a, h2 b, float c) {
    return __builtin_fmaf((float)a[1], (float)b[1],
           __builtin_fmaf((float)a[0], (float)b[0], c));
}
#endif

__device__ __forceinline__ h2 u2h2(unsigned int u) { return __builtin_bit_cast(h2, u); }
__device__ __forceinline__ unsigned int pk16(float x, float y) {
    unsigned int lo = __half_as_ushort(__float2half_rn(x));
    unsigned int hi = __half_as_ushort(__float2half_rn(y));
    return lo | (hi << 16);
}

// Exchange with lane^1 on the VALU: v_mov_b32 dpp quad_perm:[1,0,3,2]
// (ctrl 0xB1). ISA-documented: out[lane] = in[(lane&~3) | sel[lane&3]],
// sel = {1,0,3,2} -> adjacent-pair swap. 1-cycle, no DS pipe, all lanes
// active so row_mask/bank_mask 0xF and bound_ctrl irrelevant.
__device__ __forceinline__ float dpp_swap1(float x) {
    return __builtin_bit_cast(float, __builtin_amdgcn_mov_dpp(
        __builtin_bit_cast(int, x), 0xB1, 0xF, 0xF, false));
}

// Compiler-only memory fence (no instruction, doesn't drain vmcnt); DS ops
// are in-order per wave. Correctness-critical around h broadcasts (R4).
#define LDS_ORDER() asm volatile("" ::: "memory")

// ---------------------------------------------------------------------------
// Kernel 1: gx[row][n] = sum_k x[row][k]*Wih0[n][k] + bih0[n] + bhh0[n]
// Output fp16 u32 PAIR-LANE layout: for lane l = (j = l>>1, p = l&1):
//   gxu[row*64 + l] = pk16( col (p?32+j:j),  col (p?96+j:64+j) )
//   i.e. p=0 carries (i_j, g_j), p=1 carries (f_j, o_j).
// ---------------------------------------------------------------------------
__global__ __launch_bounds__(256) void xproj_kernel(
    const float* __restrict__ x,
    const float* __restrict__ Wih0,
    const float* __restrict__ bih0,
    const float* __restrict__ bhh0,
    unsigned int* __restrict__ gxu)
{
    __shared__ float xs[64][66];
    __shared__ float wt[64][132];   // Wih0 transposed: wt[k][n]

    const int tid = threadIdx.x;
    const size_t row0 = (size_t)blockIdx.x * 64;

    #pragma unroll
    for (int i = 0; i < 8; ++i) {
        int f4 = tid + i * 256;
        int n  = f4 >> 4;
        int k4 = (f4 & 15) << 2;
        float4 v = reinterpret_cast<const float4*>(Wih0)[f4];
        wt[k4 + 0][n] = v.x;
        wt[k4 + 1][n] = v.y;
        wt[k4 + 2][n] = v.z;
        wt[k4 + 3][n] = v.w;
    }
    #pragma unroll
    for (int i = 0; i < 4; ++i) {
        int f4 = tid + i * 256;
        int r  = f4 >> 4;
        int k4 = (f4 & 15) << 2;
        float4 v = reinterpret_cast<const float4*>(x + row0 * D_IN)[f4];
        xs[r][k4 + 0] = v.x;
        xs[r][k4 + 1] = v.y;
        xs[r][k4 + 2] = v.z;
        xs[r][k4 + 3] = v.w;
    }
    __syncthreads();

    const int cg = tid & 15;
    const int rg = tid >> 4;
    const int j0 = cg << 1;     // j0, j0+1
    const int r0 = rg << 2;

    // acc[r][g*2+q] -> col g*32 + j0 + q
    float acc[4][8];
    #pragma unroll
    for (int g = 0; g < 4; ++g)
        #pragma unroll
        for (int q = 0; q < 2; ++q) {
            int col = g * 32 + j0 + q;
            float bb = bih0[col] + bhh0[col];
            #pragma unroll
            for (int r = 0; r < 4; ++r) acc[r][g * 2 + q] = bb;
        }

    #pragma unroll 4
    for (int k = 0; k < 64; ++k) {
        float wv[8];
        #pragma unroll
        for (int g = 0; g < 4; ++g) {
            float2 w = *reinterpret_cast<const float2*>(&wt[k][g * 32 + j0]);
            wv[2 * g + 0] = w.x;
            wv[2 * g + 1] = w.y;
        }
        float xv[4];
        #pragma unroll
        for (int r = 0; r < 4; ++r) xv[r] = xs[r0 + r][k];
        #pragma unroll
        for (int r = 0; r < 4; ++r)
            #pragma unroll
            for (int c = 0; c < 8; ++c)
                acc[r][c] = __builtin_fmaf(xv[r], wv[c], acc[r][c]);
    }

    // pair-lane pack: lane l = 2*(j0+q)+p
    //  p=0: (i,g) = (acc[q],   acc[4+q]);  p=1: (f,o) = (acc[2+q], acc[6+q])
    #pragma unroll
    for (int r = 0; r < 4; ++r) {
        size_t row = row0 + r0 + r;
        uint4 pk;
        pk.x = pk16(acc[r][0], acc[r][4]);   // q=0, p=0
        pk.y = pk16(acc[r][2], acc[r][6]);   // q=0, p=1
        pk.z = pk16(acc[r][1], acc[r][5]);   // q=1, p=0
        pk.w = pk16(acc[r][3], acc[r][7]);   // q=1, p=1
        *reinterpret_cast<uint4*>(gxu + row * 64 + 2 * j0) = pk;
    }
}

// ---------------------------------------------------------------------------
// Kernel 2: fused 2-layer LSTM scan + FC. ONE WAVE PER BATCH ROW (512 blocks,
// 2 waves/CU). PAIR-LANE mapping: lane = 2j+p; p=0 owns gate rows {i_j, g_j},
// p=1 owns {f_j, o_j}. Gate combine = DPP quad_perm swap with lane^1 (VALU,
// ~1cyc) -- replaces the 4 ds_bpermute (~120cyc DS latency) per step of R10.
// LAYER-SKEWED schedule as R10: iteration t runs L0-act(t) || L1-act(t-1),
// one fenced LDS window broadcasts h0(t)+h1(t-1), then all dots. Weights
// pinned (96 u32 fp16x2, shared k-order chains -> bit-identical results).
// ---------------------------------------------------------------------------
__global__ __launch_bounds__(64, 1) void lstm_scan_kernel(
    const unsigned int* __restrict__ gxu,
    const float* __restrict__ Whh0,
    const float* __restrict__ Wih1,
    const float* __restrict__ Whh1,
    const float* __restrict__ bih1,
    const float* __restrict__ bhh1,
    const float* __restrict__ Wfc,
    const float* __restrict__ bfc,
    float* __restrict__ out)
{
    const int lane = threadIdx.x;
    const int j    = lane >> 1;
    const int p    = lane & 1;
    const int b    = blockIdx.x;
    const int rA   = p ? (32 + j) : j;    // gateA row: p=0 -> i_j, p=1 -> f_j
    const int rB   = rA + 64;             // gateB row: p=0 -> g_j, p=1 -> o_j

    __shared__ unsigned short h0sm[32];
    __shared__ unsigned short h1sm[32];

    // per-lane weights: 2 gate rows x 3 matrices, packed fp16 pairs in u32
    unsigned int wh0A[16], wh0B[16], wi1A[16], wi1B[16], wh1A[16], wh1B[16];
    #pragma unroll
    for (int k4 = 0; k4 < 8; ++k4) {
        float4 v;
        v = reinterpret_cast<const float4*>(Whh0 + rA * 32)[k4];
        wh0A[2*k4+0] = pk16(v.x, v.y);  wh0A[2*k4+1] = pk16(v.z, v.w);
        v = reinterpret_cast<const float4*>(Whh0 + rB * 32)[k4];
        wh0B[2*k4+0] = pk16(v.x, v.y);  wh0B[2*k4+1] = pk16(v.z, v.w);
        v = reinterpret_cast<const float4*>(Wih1 + rA * 32)[k4];
        wi1A[2*k4+0] = pk16(v.x, v.y);  wi1A[2*k4+1] = pk16(v.z, v.w);
        v = reinterpret_cast<const float4*>(Wih1 + rB * 32)[k4];
        wi1B[2*k4+0] = pk16(v.x, v.y);  wi1B[2*k4+1] = pk16(v.z, v.w);
        v = reinterpret_cast<const float4*>(Whh1 + rA * 32)[k4];
        wh1A[2*k4+0] = pk16(v.x, v.y);  wh1A[2*k4+1] = pk16(v.z, v.w);
        v = reinterpret_cast<const float4*>(Whh1 + rB * 32)[k4];
        wh1B[2*k4+0] = pk16(v.x, v.y);  wh1B[2*k4+1] = pk16(v.z, v.w);
    }
    // PIN: opaque pass-through; results can't be rematerialized -> stay live.
    #pragma unroll
    for (int k = 0; k < 16; ++k) {
        asm volatile("" : "+v"(wh0A[k]), "+v"(wh0B[k]),
                          "+v"(wi1A[k]), "+v"(wi1B[k]),
                          "+v"(wh1A[k]), "+v"(wh1B[k]));
    }

    const float b1A = bih1[rA] + bhh1[rA];
    const float b1B = bih1[rB] + bhh1[rB];

    // gateA (i or f): always sigmoid. gateB: p=0 -> tanh (g), p=1 -> sigmoid (o).
    const float sclB = p ? -1.44269504088896340736f : -2.88539008177792681472f;
    const float mulB = p ?  1.0f : 2.0f;
    const float addB = p ?  0.0f : -1.0f;

    h2 h0p[16], h1p[16];
    #pragma unroll
    for (int k = 0; k < 16; ++k) { h0p[k] = (h2){0, 0}; h1p[k] = (h2){0, 0}; }
    float c0 = 0.f, c1 = 0.f;
    float h1cur = 0.f;                 // h1(t-1); = h1(-1) = 0 at t=0

    const unsigned int* gptr = gxu + (size_t)b * S_LEN * 64 + lane;
    h2 gfirst = u2h2(gptr[0]);
    float aA = (float)gfirst[0];       // L0 preacts for step t (t=0: h0(-1)=0)
    float aB = (float)gfirst[1];
    float qA = 0.f, qB = 0.f;          // L1 preacts for step t-1 (valid t>0)
    unsigned int gnext = gptr[64];     // g(t+1), in flight

    for (int t = 0; t < S_LEN; ++t) {
        // prefetch g(t+2)
        const int tn2 = (t + 2 < S_LEN) ? (t + 2) : (S_LEN - 1);
        const unsigned int gn2 = gptr[(size_t)tn2 * 64];

        // ---- L0 act chain for step t: acts + DPP pair-swap combine
        const float vA = fsig(aA);                    // i (p=0) or f (p=1)
        float vB;
        { float e = __builtin_amdgcn_exp2f(sclB * aB);
          vB = __builtin_fmaf(mulB, __builtin_amdgcn_rcpf(1.0f + e), addB); }
        const float nA = dpp_swap1(vA);
        const float nB = dpp_swap1(vB);
        const float iv = p ? nA : vA;
        const float fv = p ? vA : nA;
        const float gv = p ? nB : vB;
        const float ov = p ? vB : nB;
        c0 = __builtin_fmaf(fv, c0, iv * gv);         // identical in pair
        const float h0 = ov * ftanh(c0);

        // ---- L1 act chain for step t-1 (parallel with the L0 chain)
        if (t > 0) {
            const float wA = fsig(qA);
            float wB;
            { float e = __builtin_amdgcn_exp2f(sclB * qB);
              wB = __builtin_fmaf(mulB, __builtin_amdgcn_rcpf(1.0f + e), addB); }
            const float mA = dpp_swap1(wA);
            const float mB = dpp_swap1(wB);
            const float iv1 = p ? mA : wA;
            const float fv1 = p ? wA : mA;
            const float gv1 = p ? mB : wB;
            const float ov1 = p ? wB : mB;
            c1 = __builtin_fmaf(fv1, c1, iv1 * gv1);
            h1cur = ov1 * ftanh(c1);                  // h1(t-1)
        }

        // ---- SINGLE broadcast window: h0(t) and h1(t-1) together.
        //      Both pair lanes store the same value to the same address.
        LDS_ORDER();
        h0sm[j] = (unsigned short)__half_as_ushort(__float2half_rn(h0));
        h1sm[j] = (unsigned short)__half_as_ushort(__float2half_rn(h1cur));
        LDS_ORDER();
        {
            const uint4* hp0 = reinterpret_cast<const uint4*>(h0sm);
            const uint4* hp1 = reinterpret_cast<const uint4*>(h1sm);
            uint4 a0 = hp0[0], a1 = hp0[1], a2 = hp0[2], a3 = hp0[3];
            uint4 d0 = hp1[0], d1 = hp1[1], d2 = hp1[2], d3 = hp1[3];
            h0p[ 0]=u2h2(a0.x); h0p[ 1]=u2h2(a0.y); h0p[ 2]=u2h2(a0.z); h0p[ 3]=u2h2(a0.w);
            h0p[ 4]=u2h2(a1.x); h0p[ 5]=u2h2(a1.y); h0p[ 6]=u2h2(a1.z); h0p[ 7]=u2h2(a1.w);
            h0p[ 8]=u2h2(a2.x); h0p[ 9]=u2h2(a2.y); h0p[10]=u2h2(a2.z); h0p[11]=u2h2(a2.w);
            h0p[12]=u2h2(a3.x); h0p[13]=u2h2(a3.y); h0p[14]=u2h2(a3.z); h0p[15]=u2h2(a3.w);
            h1p[ 0]=u2h2(d0.x); h1p[ 1]=u2h2(d0.y); h1p[ 2]=u2h2(d0.z); h1p[ 3]=u2h2(d0.w);
            h1p[ 4]=u2h2(d1.x); h1p[ 5]=u2h2(d1.y); h1p[ 6]=u2h2(d1.z); h1p[ 7]=u2h2(d1.w);
            h1p[ 8]=u2h2(d2.x); h1p[ 9]=u2h2(d2.y); h1p[10]=u2h2(d2.z); h1p[11]=u2h2(d2.w);
            h1p[12]=u2h2(d3.x); h1p[13]=u2h2(d3.y); h1p[14]=u2h2(d3.z); h1p[15]=u2h2(d3.w);
        }

        // ---- Dots: L0 for step t+1 (gx(t+1) + Whh0.h0(t)) and
        //            L1 for step t   (b1 + Wih1.h0(t) + Whh1.h1(t-1))
        h2 gnp = u2h2(gnext);
        float zA0 = (float)gnp[0], zA1 = 0.f;
        float zB0 = (float)gnp[1], zB1 = 0.f;
        float qA0 = b1A, qA1 = 0.f, qB0 = b1B, qB1 = 0.f;
        #pragma unroll
        for (int k = 0; k < 16; k += 2) {
            zA0 = fdot2(h0p[k],   u2h2(wh0A[k]),   zA0);
            zA1 = fdot2(h0p[k+1], u2h2(wh0A[k+1]), zA1);
            zB0 = fdot2(h0p[k],   u2h2(wh0B[k]),   zB0);
            zB1 = fdot2(h0p[k+1], u2h2(wh0B[k+1]), zB1);
            qA0 = fdot2(h0p[k],   u2h2(wi1A[k]),   qA0);
            qA1 = fdot2(h0p[k+1], u2h2(wi1A[k+1]), qA1);
            qB0 = fdot2(h0p[k],   u2h2(wi1B[k]),   qB0);
            qB1 = fdot2(h0p[k+1], u2h2(wi1B[k+1]), qB1);
        }
        #pragma unroll
        for (int k = 0; k < 16; k += 2) {
            qA0 = fdot2(h1p[k],   u2h2(wh1A[k]),   qA0);
            qA1 = fdot2(h1p[k+1], u2h2(wh1A[k+1]), qA1);
            qB0 = fdot2(h1p[k],   u2h2(wh1B[k]),   qB0);
            qB1 = fdot2(h1p[k+1], u2h2(wh1B[k+1]), qB1);
        }

        aA = zA0 + zA1;  aB = zB0 + zB1;
        qA = qA0 + qA1;  qB = qB0 + qB1;
        gnext = gn2;
    }

    // ---- Epilogue: final L1 act for step S-1
    float h1last;
    {
        const float wA = fsig(qA);
        float wB;
        { float e = __builtin_amdgcn_exp2f(sclB * qB);
          wB = __builtin_fmaf(mulB, __builtin_amdgcn_rcpf(1.0f + e), addB); }
        const float mA = dpp_swap1(wA);
        const float mB = dpp_swap1(wB);
        const float iv1 = p ? mA : wA;
        const float fv1 = p ? wA : mA;
        const float gv1 = p ? mB : wB;
        const float ov1 = p ? wB : mB;
        c1 = __builtin_fmaf(fv1, c1, iv1 * gv1);
        h1last = ov1 * ftanh(c1);
    }

    // ---- FC epilogue: pair lanes both hold h1[j]; mask odd lanes to zero
    //      and reduce across all 64 lanes.
    float pFC = p ? 0.0f : h1last * Wfc[j];
    pFC += __shfl_xor(pFC, 32);
    pFC += __shfl_xor(pFC, 16);
    pFC += __shfl_xor(pFC, 8);
    pFC += __shfl_xor(pFC, 4);
    pFC += __shfl_xor(pFC, 2);
    pFC += __shfl_xor(pFC, 1);
    if (lane == 0) out[b] = pFC + bfc[0];
}

extern "C" void kernel_launch(void* const* d_in, const int* in_sizes, int n_in,
                              void* d_out, int out_size, void* d_ws, size_t ws_size,
                              hipStream_t stream) {
    (void)in_sizes; (void)n_in; (void)out_size;
    const float* x    = (const float*)d_in[0];
    const float* Wih0 = (const float*)d_in[1];
    const float* Whh0 = (const float*)d_in[2];
    const float* bih0 = (const float*)d_in[3];
    const float* bhh0 = (const float*)d_in[4];
    const float* Wih1 = (const float*)d_in[5];
    const float* Whh1 = (const float*)d_in[6];
    const float* bih1 = (const float*)d_in[7];
    const float* bhh1 = (const float*)d_in[8];
    const float* Wfc  = (const float*)d_in[9];
    const float* bfc  = (const float*)d_in[10];
    float* out = (float*)d_out;

    const size_t need = (size_t)B_SZ * S_LEN * 64 * sizeof(unsigned int);  // 64 MB
    if (ws_size < need) return;
    unsigned int* gxu = (unsigned int*)d_ws;

    hipLaunchKernelGGL(xproj_kernel, dim3((B_SZ * S_LEN) / 64), dim3(256), 0, stream,
                       x, Wih0, bih0, bhh0, gxu);
    hipLaunchKernelGGL(lstm_scan_kernel, dim3(B_SZ), dim3(64), 0, stream,
                       gxu, Whh0, Wih1, Whh1, bih1, bhh1, Wfc, bfc, out);
}

// Round 12
// 271.129 us; speedup vs baseline: 1.7121x; 1.0460x over previous
//
#include <hip/hip_runtime.h>
#include <hip/hip_fp16.h>

#define B_SZ  512
#define S_LEN 512
#define D_IN  64
#define H_DIM 32

typedef _Float16 h2 __attribute__((ext_vector_type(2)));

__device__ __forceinline__ float fsig(float x) {
    float e = __builtin_amdgcn_exp2f(x * -1.44269504088896340736f);
    return __builtin_amdgcn_rcpf(1.0f + e);
}
__device__ __forceinline__ float ftanh(float x) {
    float e = __builtin_amdgcn_exp2f(x * -2.88539008177792681472f);
    return __builtin_fmaf(2.0f, __builtin_amdgcn_rcpf(1.0f + e), -1.0f);
}

#if __has_builtin(__builtin_amdgcn_fdot2)
__device__ __forceinline__ float fdot2(h2 a, h2 b, float c) {
    return __builtin_amdgcn_fdot2(a, b, c, false);   // v_dot2_f32_f16
}
#else
__device__ __forceinline__ float fdot2(h2 a, h2 b, float c) {
    return __builtin_fmaf((float)a[1], (float)b[1],
           __builtin_fmaf((float)a[0], (float)b[0], c));
}
#endif

__device__ __forceinline__ h2 u2h2(unsigned int u) { return __builtin_bit_cast(h2, u); }
__device__ __forceinline__ unsigned int pk16(float x, float y) {
    unsigned int lo = __half_as_ushort(__float2half_rn(x));
    unsigned int hi = __half_as_ushort(__float2half_rn(y));
    return lo | (hi << 16);
}

// Exchange with lane^1 on the VALU: v_mov_b32 dpp quad_perm:[1,0,3,2].
__device__ __forceinline__ float dpp_swap1(float x) {
    return __builtin_bit_cast(float, __builtin_amdgcn_mov_dpp(
        __builtin_bit_cast(int, x), 0xB1, 0xF, 0xF, false));
}

// Compiler-only memory fence (no instruction, doesn't drain vmcnt).
#define LDS_ORDER() asm volatile("" ::: "memory")
// LDS-drain + compiler fence, WITHOUT vmcnt drain (gx prefetch stays live).
#define LGKM_FENCE() asm volatile("s_waitcnt lgkmcnt(0)" ::: "memory")

// ---------------------------------------------------------------------------
// Kernel 1: gx[row][n] = sum_k x[row][k]*Wih0[n][k] + bih0[n] + bhh0[n]
// Output fp16 u32 PAIR-LANE layout: for lane l = (j = l>>1, p = l&1):
//   gxu[row*64 + l] = pk16( col (p?32+j:j),  col (p?96+j:64+j) )
// ---------------------------------------------------------------------------
__global__ __launch_bounds__(256) void xproj_kernel(
    const float* __restrict__ x,
    const float* __restrict__ Wih0,
    const float* __restrict__ bih0,
    const float* __restrict__ bhh0,
    unsigned int* __restrict__ gxu)
{
    __shared__ float xs[64][66];
    __shared__ float wt[64][132];   // Wih0 transposed: wt[k][n]

    const int tid = threadIdx.x;
    const size_t row0 = (size_t)blockIdx.x * 64;

    #pragma unroll
    for (int i = 0; i < 8; ++i) {
        int f4 = tid + i * 256;
        int n  = f4 >> 4;
        int k4 = (f4 & 15) << 2;
        float4 v = reinterpret_cast<const float4*>(Wih0)[f4];
        wt[k4 + 0][n] = v.x;
        wt[k4 + 1][n] = v.y;
        wt[k4 + 2][n] = v.z;
        wt[k4 + 3][n] = v.w;
    }
    #pragma unroll
    for (int i = 0; i < 4; ++i) {
        int f4 = tid + i * 256;
        int r  = f4 >> 4;
        int k4 = (f4 & 15) << 2;
        float4 v = reinterpret_cast<const float4*>(x + row0 * D_IN)[f4];
        xs[r][k4 + 0] = v.x;
        xs[r][k4 + 1] = v.y;
        xs[r][k4 + 2] = v.z;
        xs[r][k4 + 3] = v.w;
    }
    __syncthreads();

    const int cg = tid & 15;
    const int rg = tid >> 4;
    const int j0 = cg << 1;     // j0, j0+1
    const int r0 = rg << 2;

    float acc[4][8];
    #pragma unroll
    for (int g = 0; g < 4; ++g)
        #pragma unroll
        for (int q = 0; q < 2; ++q) {
            int col = g * 32 + j0 + q;
            float bb = bih0[col] + bhh0[col];
            #pragma unroll
            for (int r = 0; r < 4; ++r) acc[r][g * 2 + q] = bb;
        }

    #pragma unroll 4
    for (int k = 0; k < 64; ++k) {
        float wv[8];
        #pragma unroll
        for (int g = 0; g < 4; ++g) {
            float2 w = *reinterpret_cast<const float2*>(&wt[k][g * 32 + j0]);
            wv[2 * g + 0] = w.x;
            wv[2 * g + 1] = w.y;
        }
        float xv[4];
        #pragma unroll
        for (int r = 0; r < 4; ++r) xv[r] = xs[r0 + r][k];
        #pragma unroll
        for (int r = 0; r < 4; ++r)
            #pragma unroll
            for (int c = 0; c < 8; ++c)
                acc[r][c] = __builtin_fmaf(xv[r], wv[c], acc[r][c]);
    }

    #pragma unroll
    for (int r = 0; r < 4; ++r) {
        size_t row = row0 + r0 + r;
        uint4 pk;
        pk.x = pk16(acc[r][0], acc[r][4]);   // q=0, p=0: (i,g)
        pk.y = pk16(acc[r][2], acc[r][6]);   // q=0, p=1: (f,o)
        pk.z = pk16(acc[r][1], acc[r][5]);   // q=1, p=0
        pk.w = pk16(acc[r][3], acc[r][7]);   // q=1, p=1
        *reinterpret_cast<uint4*>(gxu + row * 64 + 2 * j0) = pk;
    }
}

// ---------------------------------------------------------------------------
// Kernel 2: fused 2-layer LSTM scan + FC. PRODUCER-CONSUMER WAVES:
// block = 128 threads = 2 waves = ONE batch row; 512 blocks = 1024 waves
// (1/SIMD, full machine; R11 had 512 waves = half idle).
//   wave0 = layer 0: act -> h0(t) -> h0buf[t&1] -> own 32 z-dots.
//   wave1 = layer 1 (skewed: consumes h0(t-1) from h0buf[(t-1)&1]) + FC.
// Sync: 1 raw s_barrier/step with lgkmcnt(0) only (vmcnt untouched -> gx
// prefetch stays in flight). Double-buffer parity makes writes/reads
// race-free; barrier separates iterations. Pair-lane mapping + DPP combine
// as R11; weights pinned per wave (32 / 64 u32).
// ---------------------------------------------------------------------------
__global__ __launch_bounds__(128, 1) void lstm_scan_kernel(
    const unsigned int* __restrict__ gxu,
    const float* __restrict__ Whh0,
    const float* __restrict__ Wih1,
    const float* __restrict__ Whh1,
    const float* __restrict__ bih1,
    const float* __restrict__ bhh1,
    const float* __restrict__ Wfc,
    const float* __restrict__ bfc,
    float* __restrict__ out)
{
    const int tid  = threadIdx.x;
    const int lane = tid & 63;
    const int j    = lane >> 1;
    const int p    = lane & 1;
    const int b    = blockIdx.x;
    const int rA   = p ? (32 + j) : j;    // gateA row: p=0 -> i_j, p=1 -> f_j
    const int rB   = rA + 64;             // gateB row: p=0 -> g_j, p=1 -> o_j

    __shared__ unsigned short h0buf[2][32];   // cross-wave, double-buffered
    __shared__ unsigned short h1sm[32];       // wave1-private

    if (tid < 32) { h0buf[0][tid] = 0; h0buf[1][tid] = 0; h1sm[tid] = 0; }
    __syncthreads();

    // gateA (i or f): sigmoid. gateB: p=0 -> tanh (g), p=1 -> sigmoid (o).
    const float sclB = p ? -1.44269504088896340736f : -2.88539008177792681472f;
    const float mulB = p ?  1.0f : 2.0f;
    const float addB = p ?  0.0f : -1.0f;

    if (tid < 64) {
        // ================= WAVE 0 : layer 0 producer =================
        unsigned int wh0A[16], wh0B[16];
        #pragma unroll
        for (int k4 = 0; k4 < 8; ++k4) {
            float4 v;
            v = reinterpret_cast<const float4*>(Whh0 + rA * 32)[k4];
            wh0A[2*k4+0] = pk16(v.x, v.y);  wh0A[2*k4+1] = pk16(v.z, v.w);
            v = reinterpret_cast<const float4*>(Whh0 + rB * 32)[k4];
            wh0B[2*k4+0] = pk16(v.x, v.y);  wh0B[2*k4+1] = pk16(v.z, v.w);
        }
        #pragma unroll
        for (int k = 0; k < 16; ++k)
            asm volatile("" : "+v"(wh0A[k]), "+v"(wh0B[k]));

        h2 h0p[16];
        #pragma unroll
        for (int k = 0; k < 16; ++k) h0p[k] = (h2){0, 0};
        float c0 = 0.f;

        const unsigned int* gptr = gxu + (size_t)b * S_LEN * 64 + lane;
        h2 g0 = u2h2(gptr[0]);
        float aA = (float)g0[0];          // L0 preacts t=0 (h0(-1)=0)
        float aB = (float)g0[1];
        unsigned int gnext = gptr[64];    // g(t+1), in flight

        for (int t = 0; t < S_LEN; ++t) {
            const int tn2 = (t + 2 < S_LEN) ? (t + 2) : (S_LEN - 1);
            const unsigned int gn2 = gptr[(size_t)tn2 * 64];

            // act chain + DPP combine + cell + h0(t)
            const float vA = fsig(aA);
            float vB;
            { float e = __builtin_amdgcn_exp2f(sclB * aB);
              vB = __builtin_fmaf(mulB, __builtin_amdgcn_rcpf(1.0f + e), addB); }
            const float nA = dpp_swap1(vA);
            const float nB = dpp_swap1(vB);
            const float iv = p ? nA : vA;
            const float fv = p ? vA : nA;
            const float gv = p ? nB : vB;
            const float ov = p ? vB : nB;
            c0 = __builtin_fmaf(fv, c0, iv * gv);
            const float h0 = ov * ftanh(c0);

            // publish h0(t) to buf[t&1]; read back own packed copy
            unsigned short* hb = &h0buf[t & 1][0];
            LDS_ORDER();
            hb[j] = (unsigned short)__half_as_ushort(__float2half_rn(h0));
            LDS_ORDER();
            {
                const uint4* hp = reinterpret_cast<const uint4*>(hb);
                uint4 a0 = hp[0], a1 = hp[1], a2 = hp[2], a3 = hp[3];
                h0p[ 0]=u2h2(a0.x); h0p[ 1]=u2h2(a0.y); h0p[ 2]=u2h2(a0.z); h0p[ 3]=u2h2(a0.w);
                h0p[ 4]=u2h2(a1.x); h0p[ 5]=u2h2(a1.y); h0p[ 6]=u2h2(a1.z); h0p[ 7]=u2h2(a1.w);
                h0p[ 8]=u2h2(a2.x); h0p[ 9]=u2h2(a2.y); h0p[10]=u2h2(a2.z); h0p[11]=u2h2(a2.w);
                h0p[12]=u2h2(a3.x); h0p[13]=u2h2(a3.y); h0p[14]=u2h2(a3.z); h0p[15]=u2h2(a3.w);
            }

            // z-dots: aA(t+1) = gx(t+1) + Whh0 . h0(t)
            h2 gnp = u2h2(gnext);
            float zA0 = (float)gnp[0], zA1 = 0.f;
            float zB0 = (float)gnp[1], zB1 = 0.f;
            #pragma unroll
            for (int k = 0; k < 16; k += 2) {
                zA0 = fdot2(h0p[k],   u2h2(wh0A[k]),   zA0);
                zA1 = fdot2(h0p[k+1], u2h2(wh0A[k+1]), zA1);
                zB0 = fdot2(h0p[k],   u2h2(wh0B[k]),   zB0);
                zB1 = fdot2(h0p[k+1], u2h2(wh0B[k+1]), zB1);
            }
            aA = zA0 + zA1;  aB = zB0 + zB1;
            gnext = gn2;

            LGKM_FENCE();                     // LDS drained, vmcnt untouched
            __builtin_amdgcn_s_barrier();
        }
    } else {
        // ================= WAVE 1 : layer 1 consumer + FC =================
        unsigned int wi1A[16], wi1B[16], wh1A[16], wh1B[16];
        #pragma unroll
        for (int k4 = 0; k4 < 8; ++k4) {
            float4 v;
            v = reinterpret_cast<const float4*>(Wih1 + rA * 32)[k4];
            wi1A[2*k4+0] = pk16(v.x, v.y);  wi1A[2*k4+1] = pk16(v.z, v.w);
            v = reinterpret_cast<const float4*>(Wih1 + rB * 32)[k4];
            wi1B[2*k4+0] = pk16(v.x, v.y);  wi1B[2*k4+1] = pk16(v.z, v.w);
            v = reinterpret_cast<const float4*>(Whh1 + rA * 32)[k4];
            wh1A[2*k4+0] = pk16(v.x, v.y);  wh1A[2*k4+1] = pk16(v.z, v.w);
            v = reinterpret_cast<const float4*>(Whh1 + rB * 32)[k4];
            wh1B[2*k4+0] = pk16(v.x, v.y);  wh1B[2*k4+1] = pk16(v.z, v.w);
        }
        #pragma unroll
        for (int k = 0; k < 16; ++k)
            asm volatile("" : "+v"(wi1A[k]), "+v"(wi1B[k]),
                              "+v"(wh1A[k]), "+v"(wh1B[k]));

        const float b1A = bih1[rA] + bhh1[rA];
        const float b1B = bih1[rB] + bhh1[rB];

        h2 h1p[16];
        #pragma unroll
        for (int k = 0; k < 16; ++k) h1p[k] = (h2){0, 0};   // h1(-1) = 0
        float c1 = 0.f;

        for (int t = 0; t < S_LEN; ++t) {
            if (t > 0) {
                // h0(t-1) from the buffer written last iteration (parity-safe)
                LDS_ORDER();
                const uint4* hq = reinterpret_cast<const uint4*>(&h0buf[(t - 1) & 1][0]);
                uint4 d0 = hq[0], d1 = hq[1], d2 = hq[2], d3 = hq[3];

                // Whh1 . h1(t-2) first: independent of the reads above,
                // covers their latency.
                float qA0 = b1A, qA1 = 0.f, qB0 = b1B, qB1 = 0.f;
                #pragma unroll
                for (int k = 0; k < 16; k += 2) {
                    qA0 = fdot2(h1p[k],   u2h2(wh1A[k]),   qA0);
                    qA1 = fdot2(h1p[k+1], u2h2(wh1A[k+1]), qA1);
                    qB0 = fdot2(h1p[k],   u2h2(wh1B[k]),   qB0);
                    qB1 = fdot2(h1p[k+1], u2h2(wh1B[k+1]), qB1);
                }

                h2 h0q[16];
                h0q[ 0]=u2h2(d0.x); h0q[ 1]=u2h2(d0.y); h0q[ 2]=u2h2(d0.z); h0q[ 3]=u2h2(d0.w);
                h0q[ 4]=u2h2(d1.x); h0q[ 5]=u2h2(d1.y); h0q[ 6]=u2h2(d1.z); h0q[ 7]=u2h2(d1.w);
                h0q[ 8]=u2h2(d2.x); h0q[ 9]=u2h2(d2.y); h0q[10]=u2h2(d2.z); h0q[11]=u2h2(d2.w);
                h0q[12]=u2h2(d3.x); h0q[13]=u2h2(d3.y); h0q[14]=u2h2(d3.z); h0q[15]=u2h2(d3.w);

                #pragma unroll
                for (int k = 0; k < 16; k += 2) {
                    qA0 = fdot2(h0q[k],   u2h2(wi1A[k]),   qA0);
                    qA1 = fdot2(h0q[k+1], u2h2(wi1A[k+1]), qA1);
                    qB0 = fdot2(h0q[k],   u2h2(wi1B[k]),   qB0);
                    qB1 = fdot2(h0q[k+1], u2h2(wi1B[k+1]), qB1);
                }
                const float qA = qA0 + qA1;
                const float qB = qB0 + qB1;

                const float wA = fsig(qA);
                float wB;
                { float e = __builtin_amdgcn_exp2f(sclB * qB);
                  wB = __builtin_fmaf(mulB, __builtin_amdgcn_rcpf(1.0f + e), addB); }
                const float mA = dpp_swap1(wA);
                const float mB = dpp_swap1(wB);
                const float iv1 = p ? mA : wA;
                const float fv1 = p ? wA : mA;
                const float gv1 = p ? mB : wB;
                const float ov1 = p ? wB : mB;
                c1 = __builtin_fmaf(fv1, c1, iv1 * gv1);
                const float h1 = ov1 * ftanh(c1);    // h1(t-1)

                // own broadcast for next iteration's Whh1 dots
                LDS_ORDER();
                h1sm[j] = (unsigned short)__half_as_ushort(__float2half_rn(h1));
                LDS_ORDER();
                {
                    const uint4* hp = reinterpret_cast<const uint4*>(h1sm);
                    uint4 a0 = hp[0], a1 = hp[1], a2 = hp[2], a3 = hp[3];
                    h1p[ 0]=u2h2(a0.x); h1p[ 1]=u2h2(a0.y); h1p[ 2]=u2h2(a0.z); h1p[ 3]=u2h2(a0.w);
                    h1p[ 4]=u2h2(a1.x); h1p[ 5]=u2h2(a1.y); h1p[ 6]=u2h2(a1.z); h1p[ 7]=u2h2(a1.w);
                    h1p[ 8]=u2h2(a2.x); h1p[ 9]=u2h2(a2.y); h1p[10]=u2h2(a2.z); h1p[11]=u2h2(a2.w);
                    h1p[12]=u2h2(a3.x); h1p[13]=u2h2(a3.y); h1p[14]=u2h2(a3.z); h1p[15]=u2h2(a3.w);
                }
            }
            LGKM_FENCE();
            __builtin_amdgcn_s_barrier();
        }

        // ---- epilogue: L1 step S-1 (h0(S-1) published at iter S-1) ----
        LDS_ORDER();
        const uint4* hq = reinterpret_cast<const uint4*>(&h0buf[(S_LEN - 1) & 1][0]);
        uint4 d0 = hq[0], d1 = hq[1], d2 = hq[2], d3 = hq[3];
        float qA0 = b1A, qA1 = 0.f, qB0 = b1B, qB1 = 0.f;
        #pragma unroll
        for (int k = 0; k < 16; k += 2) {
            qA0 = fdot2(h1p[k],   u2h2(wh1A[k]),   qA0);
            qA1 = fdot2(h1p[k+1], u2h2(wh1A[k+1]), qA1);
            qB0 = fdot2(h1p[k],   u2h2(wh1B[k]),   qB0);
            qB1 = fdot2(h1p[k+1], u2h2(wh1B[k+1]), qB1);
        }
        h2 h0q[16];
        h0q[ 0]=u2h2(d0.x); h0q[ 1]=u2h2(d0.y); h0q[ 2]=u2h2(d0.z); h0q[ 3]=u2h2(d0.w);
        h0q[ 4]=u2h2(d1.x); h0q[ 5]=u2h2(d1.y); h0q[ 6]=u2h2(d1.z); h0q[ 7]=u2h2(d1.w);
        h0q[ 8]=u2h2(d2.x); h0q[ 9]=u2h2(d2.y); h0q[10]=u2h2(d2.z); h0q[11]=u2h2(d2.w);
        h0q[12]=u2h2(d3.x); h0q[13]=u2h2(d3.y); h0q[14]=u2h2(d3.z); h0q[15]=u2h2(d3.w);
        #pragma unroll
        for (int k = 0; k < 16; k += 2) {
            qA0 = fdot2(h0q[k],   u2h2(wi1A[k]),   qA0);
            qA1 = fdot2(h0q[k+1], u2h2(wi1A[k+1]), qA1);
            qB0 = fdot2(h0q[k],   u2h2(wi1B[k]),   qB0);
            qB1 = fdot2(h0q[k+1], u2h2(wi1B[k+1]), qB1);
        }
        const float qA = qA0 + qA1;
        const float qB = qB0 + qB1;
        const float wA = fsig(qA);
        float wB;
        { float e = __builtin_amdgcn_exp2f(sclB * qB);
          wB = __builtin_fmaf(mulB, __builtin_amdgcn_rcpf(1.0f + e), addB); }
        const float mA = dpp_swap1(wA);
        const float mB = dpp_swap1(wB);
        const float iv1 = p ? mA : wA;
        const float fv1 = p ? wA : mA;
        const float gv1 = p ? mB : wB;
        const float ov1 = p ? wB : mB;
        c1 = __builtin_fmaf(fv1, c1, iv1 * gv1);
        const float h1last = ov1 * ftanh(c1);

        // FC: pair lanes both hold h1[j]; mask odd lanes, 64-lane reduce
        float pFC = p ? 0.0f : h1last * Wfc[j];
        pFC += __shfl_xor(pFC, 32);
        pFC += __shfl_xor(pFC, 16);
        pFC += __shfl_xor(pFC, 8);
        pFC += __shfl_xor(pFC, 4);
        pFC += __shfl_xor(pFC, 2);
        pFC += __shfl_xor(pFC, 1);
        if (lane == 0) out[b] = pFC + bfc[0];
    }
}

extern "C" void kernel_launch(void* const* d_in, const int* in_sizes, int n_in,
                              void* d_out, int out_size, void* d_ws, size_t ws_size,
                              hipStream_t stream) {
    (void)in_sizes; (void)n_in; (void)out_size;
    const float* x    = (const float*)d_in[0];
    const float* Wih0 = (const float*)d_in[1];
    const float* Whh0 = (const float*)d_in[2];
    const float* bih0 = (const float*)d_in[3];
    const float* bhh0 = (const float*)d_in[4];
    const float* Wih1 = (const float*)d_in[5];
    const float* Whh1 = (const float*)d_in[6];
    const float* bih1 = (const float*)d_in[7];
    const float* bhh1 = (const float*)d_in[8];
    const float* Wfc  = (const float*)d_in[9];
    const float* bfc  = (const float*)d_in[10];
    float* out = (float*)d_out;

    const size_t need = (size_t)B_SZ * S_LEN * 64 * sizeof(unsigned int);  // 64 MB
    if (ws_size < need) return;
    unsigned int* gxu = (unsigned int*)d_ws;

    hipLaunchKernelGGL(xproj_kernel, dim3((B_SZ * S_LEN) / 64), dim3(256), 0, stream,
                       x, Wih0, bih0, bhh0, gxu);
    hipLaunchKernelGGL(lstm_scan_kernel, dim3(B_SZ), dim3(128), 0, stream,
                       gxu, Whh0, Wih1, Whh1, bih1, bhh1, Wfc, bfc, out);
}

// Round 13
// 259.210 us; speedup vs baseline: 1.7908x; 1.0460x over previous
//
#include <hip/hip_runtime.h>
#include <hip/hip_fp16.h>

#define B_SZ  512
#define S_LEN 512
#define D_IN  64
#define H_DIM 32
#define KPIPE 8          // steps per super-step (ring depth)

typedef _Float16 h2 __attribute__((ext_vector_type(2)));

__device__ __forceinline__ float fsig(float x) {
    float e = __builtin_amdgcn_exp2f(x * -1.44269504088896340736f);
    return __builtin_amdgcn_rcpf(1.0f + e);
}
__device__ __forceinline__ float ftanh(float x) {
    float e = __builtin_amdgcn_exp2f(x * -2.88539008177792681472f);
    return __builtin_fmaf(2.0f, __builtin_amdgcn_rcpf(1.0f + e), -1.0f);
}

#if __has_builtin(__builtin_amdgcn_fdot2)
__device__ __forceinline__ float fdot2(h2 a, h2 b, float c) {
    return __builtin_amdgcn_fdot2(a, b, c, false);   // v_dot2_f32_f16
}
#else
__device__ __forceinline__ float fdot2(h2 a, h2 b, float c) {
    return __builtin_fmaf((float)a[1], (float)b[1],
           __builtin_fmaf((float)a[0], (float)b[0], c));
}
#endif

__device__ __forceinline__ h2 u2h2(unsigned int u) { return __builtin_bit_cast(h2, u); }
__device__ __forceinline__ unsigned int pk16(float x, float y) {
    unsigned int lo = __half_as_ushort(__float2half_rn(x));
    unsigned int hi = __half_as_ushort(__float2half_rn(y));
    return lo | (hi << 16);
}

// Exchange with lane^1 on the VALU: v_mov_b32 dpp quad_perm:[1,0,3,2].
__device__ __forceinline__ float dpp_swap1(float x) {
    return __builtin_bit_cast(float, __builtin_amdgcn_mov_dpp(
        __builtin_bit_cast(int, x), 0xB1, 0xF, 0xF, false));
}

// Compiler-only memory fence (no instruction, doesn't drain vmcnt).
#define LDS_ORDER() asm volatile("" ::: "memory")
// LDS-drain + compiler fence, WITHOUT vmcnt drain (gx prefetch stays live).
#define LGKM_FENCE() asm volatile("s_waitcnt lgkmcnt(0)" ::: "memory")

// ---------------------------------------------------------------------------
// Kernel 1: gx[row][n] = sum_k x[row][k]*Wih0[n][k] + bih0[n] + bhh0[n]
// Output fp16 u32 PAIR-LANE layout: for lane l = (j = l>>1, p = l&1):
//   gxu[row*64 + l] = pk16( col (p?32+j:j),  col (p?96+j:64+j) )
// ---------------------------------------------------------------------------
__global__ __launch_bounds__(256) void xproj_kernel(
    const float* __restrict__ x,
    const float* __restrict__ Wih0,
    const float* __restrict__ bih0,
    const float* __restrict__ bhh0,
    unsigned int* __restrict__ gxu)
{
    __shared__ float xs[64][66];
    __shared__ float wt[64][132];   // Wih0 transposed: wt[k][n]

    const int tid = threadIdx.x;
    const size_t row0 = (size_t)blockIdx.x * 64;

    #pragma unroll
    for (int i = 0; i < 8; ++i) {
        int f4 = tid + i * 256;
        int n  = f4 >> 4;
        int k4 = (f4 & 15) << 2;
        float4 v = reinterpret_cast<const float4*>(Wih0)[f4];
        wt[k4 + 0][n] = v.x;
        wt[k4 + 1][n] = v.y;
        wt[k4 + 2][n] = v.z;
        wt[k4 + 3][n] = v.w;
    }
    #pragma unroll
    for (int i = 0; i < 4; ++i) {
        int f4 = tid + i * 256;
        int r  = f4 >> 4;
        int k4 = (f4 & 15) << 2;
        float4 v = reinterpret_cast<const float4*>(x + row0 * D_IN)[f4];
        xs[r][k4 + 0] = v.x;
        xs[r][k4 + 1] = v.y;
        xs[r][k4 + 2] = v.z;
        xs[r][k4 + 3] = v.w;
    }
    __syncthreads();

    const int cg = tid & 15;
    const int rg = tid >> 4;
    const int j0 = cg << 1;     // j0, j0+1
    const int r0 = rg << 2;

    float acc[4][8];
    #pragma unroll
    for (int g = 0; g < 4; ++g)
        #pragma unroll
        for (int q = 0; q < 2; ++q) {
            int col = g * 32 + j0 + q;
            float bb = bih0[col] + bhh0[col];
            #pragma unroll
            for (int r = 0; r < 4; ++r) acc[r][g * 2 + q] = bb;
        }

    #pragma unroll 4
    for (int k = 0; k < 64; ++k) {
        float wv[8];
        #pragma unroll
        for (int g = 0; g < 4; ++g) {
            float2 w = *reinterpret_cast<const float2*>(&wt[k][g * 32 + j0]);
            wv[2 * g + 0] = w.x;
            wv[2 * g + 1] = w.y;
        }
        float xv[4];
        #pragma unroll
        for (int r = 0; r < 4; ++r) xv[r] = xs[r0 + r][k];
        #pragma unroll
        for (int r = 0; r < 4; ++r)
            #pragma unroll
            for (int c = 0; c < 8; ++c)
                acc[r][c] = __builtin_fmaf(xv[r], wv[c], acc[r][c]);
    }

    #pragma unroll
    for (int r = 0; r < 4; ++r) {
        size_t row = row0 + r0 + r;
        uint4 pk;
        pk.x = pk16(acc[r][0], acc[r][4]);   // q=0, p=0: (i,g)
        pk.y = pk16(acc[r][2], acc[r][6]);   // q=0, p=1: (f,o)
        pk.z = pk16(acc[r][1], acc[r][5]);   // q=1, p=0
        pk.w = pk16(acc[r][3], acc[r][7]);   // q=1, p=1
        *reinterpret_cast<uint4*>(gxu + row * 64 + 2 * j0) = pk;
    }
}

// ---------------------------------------------------------------------------
// Kernel 2: fused 2-layer LSTM scan + FC. BLOCK-PIPELINED producer-consumer:
// block = 128 threads = 2 waves = ONE batch row.
//   wave0 = layer 0, runs K=8 steps AHEAD into ring h0buf[s&1][8][32]
//           (L0's recurrence is self-contained -> no per-step sync needed).
//   wave1 = layer 1, consumes the previous super-step's 8 h0 values; + FC.
// ONE s_barrier per 8 steps (64 total vs 512 in R12) with lgkmcnt-only
// drain. Double-buffer parity keeps producer/consumer slots disjoint;
// the barrier stops wave0 recycling a buffer before wave1 drained it.
// ---------------------------------------------------------------------------
__global__ __launch_bounds__(128, 1) void lstm_scan_kernel(
    const unsigned int* __restrict__ gxu,
    const float* __restrict__ Whh0,
    const float* __restrict__ Wih1,
    const float* __restrict__ Whh1,
    const float* __restrict__ bih1,
    const float* __restrict__ bhh1,
    const float* __restrict__ Wfc,
    const float* __restrict__ bfc,
    float* __restrict__ out)
{
    const int tid  = threadIdx.x;
    const int lane = tid & 63;
    const int j    = lane >> 1;
    const int p    = lane & 1;
    const int b    = blockIdx.x;
    const int rA   = p ? (32 + j) : j;    // gateA row: p=0 -> i_j, p=1 -> f_j
    const int rB   = rA + 64;             // gateB row: p=0 -> g_j, p=1 -> o_j

    __shared__ unsigned short h0buf[2][KPIPE][32];   // ring, cross-wave
    __shared__ unsigned short h1sm[32];              // wave1-private

    // gateA (i or f): sigmoid. gateB: p=0 -> tanh (g), p=1 -> sigmoid (o).
    const float sclB = p ? -1.44269504088896340736f : -2.88539008177792681472f;
    const float mulB = p ?  1.0f : 2.0f;
    const float addB = p ?  0.0f : -1.0f;

    if (tid < 64) {
        // ================= WAVE 0 : layer 0 producer (8 steps/super) =======
        unsigned int wh0A[16], wh0B[16];
        #pragma unroll
        for (int k4 = 0; k4 < 8; ++k4) {
            float4 v;
            v = reinterpret_cast<const float4*>(Whh0 + rA * 32)[k4];
            wh0A[2*k4+0] = pk16(v.x, v.y);  wh0A[2*k4+1] = pk16(v.z, v.w);
            v = reinterpret_cast<const float4*>(Whh0 + rB * 32)[k4];
            wh0B[2*k4+0] = pk16(v.x, v.y);  wh0B[2*k4+1] = pk16(v.z, v.w);
        }
        #pragma unroll
        for (int k = 0; k < 16; ++k)
            asm volatile("" : "+v"(wh0A[k]), "+v"(wh0B[k]));

        h2 h0p[16];
        #pragma unroll
        for (int k = 0; k < 16; ++k) h0p[k] = (h2){0, 0};
        float c0 = 0.f;

        const unsigned int* gptr = gxu + (size_t)b * S_LEN * 64 + lane;
        h2 g0 = u2h2(gptr[0]);
        float aA = (float)g0[0];          // L0 preacts t=0 (h0(-1)=0)
        float aB = (float)g0[1];
        unsigned int gnext = gptr[64];    // g(t+1), in flight

        for (int s = 0; s < S_LEN / KPIPE; ++s) {
            unsigned short (*slot)[32] = h0buf[s & 1];
            #pragma unroll
            for (int u = 0; u < KPIPE; ++u) {
                const int t = s * KPIPE + u;
                const int tn2 = (t + 2 < S_LEN) ? (t + 2) : (S_LEN - 1);
                const unsigned int gn2 = gptr[(size_t)tn2 * 64];

                // act chain + DPP combine + cell + h0(t)
                const float vA = fsig(aA);
                float vB;
                { float e = __builtin_amdgcn_exp2f(sclB * aB);
                  vB = __builtin_fmaf(mulB, __builtin_amdgcn_rcpf(1.0f + e), addB); }
                const float nA = dpp_swap1(vA);
                const float nB = dpp_swap1(vB);
                const float iv = p ? nA : vA;
                const float fv = p ? vA : nA;
                const float gv = p ? nB : vB;
                const float ov = p ? vB : nB;
                c0 = __builtin_fmaf(fv, c0, iv * gv);
                const float h0 = ov * ftanh(c0);

                // publish h0(t) into the ring; read back own packed copy
                LDS_ORDER();
                slot[u][j] = (unsigned short)__half_as_ushort(__float2half_rn(h0));
                LDS_ORDER();
                {
                    const uint4* hp = reinterpret_cast<const uint4*>(&slot[u][0]);
                    uint4 a0 = hp[0], a1 = hp[1], a2 = hp[2], a3 = hp[3];
                    h0p[ 0]=u2h2(a0.x); h0p[ 1]=u2h2(a0.y); h0p[ 2]=u2h2(a0.z); h0p[ 3]=u2h2(a0.w);
                    h0p[ 4]=u2h2(a1.x); h0p[ 5]=u2h2(a1.y); h0p[ 6]=u2h2(a1.z); h0p[ 7]=u2h2(a1.w);
                    h0p[ 8]=u2h2(a2.x); h0p[ 9]=u2h2(a2.y); h0p[10]=u2h2(a2.z); h0p[11]=u2h2(a2.w);
                    h0p[12]=u2h2(a3.x); h0p[13]=u2h2(a3.y); h0p[14]=u2h2(a3.z); h0p[15]=u2h2(a3.w);
                }

                // z-dots: aA(t+1) = gx(t+1) + Whh0 . h0(t)
                h2 gnp = u2h2(gnext);
                float zA0 = (float)gnp[0], zA1 = 0.f;
                float zB0 = (float)gnp[1], zB1 = 0.f;
                #pragma unroll
                for (int k = 0; k < 16; k += 2) {
                    zA0 = fdot2(h0p[k],   u2h2(wh0A[k]),   zA0);
                    zA1 = fdot2(h0p[k+1], u2h2(wh0A[k+1]), zA1);
                    zB0 = fdot2(h0p[k],   u2h2(wh0B[k]),   zB0);
                    zB1 = fdot2(h0p[k+1], u2h2(wh0B[k+1]), zB1);
                }
                aA = zA0 + zA1;  aB = zB0 + zB1;
                gnext = gn2;
            }
            LGKM_FENCE();                     // LDS drained, vmcnt untouched
            __builtin_amdgcn_s_barrier();
        }
    } else {
        // ================= WAVE 1 : layer 1 consumer + FC ==================
        unsigned int wi1A[16], wi1B[16], wh1A[16], wh1B[16];
        #pragma unroll
        for (int k4 = 0; k4 < 8; ++k4) {
            float4 v;
            v = reinterpret_cast<const float4*>(Wih1 + rA * 32)[k4];
            wi1A[2*k4+0] = pk16(v.x, v.y);  wi1A[2*k4+1] = pk16(v.z, v.w);
            v = reinterpret_cast<const float4*>(Wih1 + rB * 32)[k4];
            wi1B[2*k4+0] = pk16(v.x, v.y);  wi1B[2*k4+1] = pk16(v.z, v.w);
            v = reinterpret_cast<const float4*>(Whh1 + rA * 32)[k4];
            wh1A[2*k4+0] = pk16(v.x, v.y);  wh1A[2*k4+1] = pk16(v.z, v.w);
            v = reinterpret_cast<const float4*>(Whh1 + rB * 32)[k4];
            wh1B[2*k4+0] = pk16(v.x, v.y);  wh1B[2*k4+1] = pk16(v.z, v.w);
        }
        #pragma unroll
        for (int k = 0; k < 16; ++k)
            asm volatile("" : "+v"(wi1A[k]), "+v"(wi1B[k]),
                              "+v"(wh1A[k]), "+v"(wh1B[k]));

        const float b1A = bih1[rA] + bhh1[rA];
        const float b1B = bih1[rB] + bhh1[rB];

        h2 h1p[16];
        #pragma unroll
        for (int k = 0; k < 16; ++k) h1p[k] = (h2){0, 0};   // h1(-1) = 0
        float c1 = 0.f;
        float h1last = 0.f;

        // consume one 8-step block published in super-step (s-1)
        auto consume8 = [&](const unsigned short (*slot)[32]) {
            // prefetch sub-step 0's h0
            uint4 d0, d1, d2, d3;
            {
                const uint4* hq = reinterpret_cast<const uint4*>(&slot[0][0]);
                d0 = hq[0]; d1 = hq[1]; d2 = hq[2]; d3 = hq[3];
            }
            #pragma unroll
            for (int u = 0; u < KPIPE; ++u) {
                h2 h0q[16];
                h0q[ 0]=u2h2(d0.x); h0q[ 1]=u2h2(d0.y); h0q[ 2]=u2h2(d0.z); h0q[ 3]=u2h2(d0.w);
                h0q[ 4]=u2h2(d1.x); h0q[ 5]=u2h2(d1.y); h0q[ 6]=u2h2(d1.z); h0q[ 7]=u2h2(d1.w);
                h0q[ 8]=u2h2(d2.x); h0q[ 9]=u2h2(d2.y); h0q[10]=u2h2(d2.z); h0q[11]=u2h2(d2.w);
                h0q[12]=u2h2(d3.x); h0q[13]=u2h2(d3.y); h0q[14]=u2h2(d3.z); h0q[15]=u2h2(d3.w);
                if (u + 1 < KPIPE) {
                    // issue next sub-step's h0 read early; latency hides
                    // under this sub-step's dots/act.
                    const uint4* hq = reinterpret_cast<const uint4*>(&slot[u + 1][0]);
                    d0 = hq[0]; d1 = hq[1]; d2 = hq[2]; d3 = hq[3];
                }

                // wi1 dots first (independent of h1 carried chain);
                // then wh1 dots on h1p (read-back latency already covered).
                float qA0 = b1A, qA1 = 0.f, qB0 = b1B, qB1 = 0.f;
                #pragma unroll
                for (int k = 0; k < 16; k += 2) {
                    qA0 = fdot2(h0q[k],   u2h2(wi1A[k]),   qA0);
                    qA1 = fdot2(h0q[k+1], u2h2(wi1A[k+1]), qA1);
                    qB0 = fdot2(h0q[k],   u2h2(wi1B[k]),   qB0);
                    qB1 = fdot2(h0q[k+1], u2h2(wi1B[k+1]), qB1);
                }
                #pragma unroll
                for (int k = 0; k < 16; k += 2) {
                    qA0 = fdot2(h1p[k],   u2h2(wh1A[k]),   qA0);
                    qA1 = fdot2(h1p[k+1], u2h2(wh1A[k+1]), qA1);
                    qB0 = fdot2(h1p[k],   u2h2(wh1B[k]),   qB0);
                    qB1 = fdot2(h1p[k+1], u2h2(wh1B[k+1]), qB1);
                }
                const float qA = qA0 + qA1;
                const float qB = qB0 + qB1;

                const float wA = fsig(qA);
                float wB;
                { float e = __builtin_amdgcn_exp2f(sclB * qB);
                  wB = __builtin_fmaf(mulB, __builtin_amdgcn_rcpf(1.0f + e), addB); }
                const float mA = dpp_swap1(wA);
                const float mB = dpp_swap1(wB);
                const float iv1 = p ? mA : wA;
                const float fv1 = p ? wA : mA;
                const float gv1 = p ? mB : wB;
                const float ov1 = p ? wB : mB;
                c1 = __builtin_fmaf(fv1, c1, iv1 * gv1);
                const float h1 = ov1 * ftanh(c1);
                h1last = h1;

                // own broadcast for next sub-step's wh1 dots
                LDS_ORDER();
                h1sm[j] = (unsigned short)__half_as_ushort(__float2half_rn(h1));
                LDS_ORDER();
                {
                    const uint4* hp = reinterpret_cast<const uint4*>(h1sm);
                    uint4 a0 = hp[0], a1 = hp[1], a2 = hp[2], a3 = hp[3];
                    h1p[ 0]=u2h2(a0.x); h1p[ 1]=u2h2(a0.y); h1p[ 2]=u2h2(a0.z); h1p[ 3]=u2h2(a0.w);
                    h1p[ 4]=u2h2(a1.x); h1p[ 5]=u2h2(a1.y); h1p[ 6]=u2h2(a1.z); h1p[ 7]=u2h2(a1.w);
                    h1p[ 8]=u2h2(a2.x); h1p[ 9]=u2h2(a2.y); h1p[10]=u2h2(a2.z); h1p[11]=u2h2(a2.w);
                    h1p[12]=u2h2(a3.x); h1p[13]=u2h2(a3.y); h1p[14]=u2h2(a3.z); h1p[15]=u2h2(a3.w);
                }
            }
        };

        for (int s = 0; s < S_LEN / KPIPE; ++s) {
            if (s > 0) consume8(h0buf[(s - 1) & 1]);
            LGKM_FENCE();
            __builtin_amdgcn_s_barrier();
        }
        // epilogue: final 8 steps from the last-produced buffer
        consume8(h0buf[(S_LEN / KPIPE - 1) & 1]);

        // FC: pair lanes both hold h1[j]; mask odd lanes, 64-lane reduce
        float pFC = p ? 0.0f : h1last * Wfc[j];
        pFC += __shfl_xor(pFC, 32);
        pFC += __shfl_xor(pFC, 16);
        pFC += __shfl_xor(pFC, 8);
        pFC += __shfl_xor(pFC, 4);
        pFC += __shfl_xor(pFC, 2);
        pFC += __shfl_xor(pFC, 1);
        if (lane == 0) out[b] = pFC + bfc[0];
    }
}

extern "C" void kernel_launch(void* const* d_in, const int* in_sizes, int n_in,
                              void* d_out, int out_size, void* d_ws, size_t ws_size,
                              hipStream_t stream) {
    (void)in_sizes; (void)n_in; (void)out_size;
    const float* x    = (const float*)d_in[0];
    const float* Wih0 = (const float*)d_in[1];
    const float* Whh0 = (const float*)d_in[2];
    const float* bih0 = (const float*)d_in[3];
    const float* bhh0 = (const float*)d_in[4];
    const float* Wih1 = (const float*)d_in[5];
    const float* Whh1 = (const float*)d_in[6];
    const float* bih1 = (const float*)d_in[7];
    const float* bhh1 = (const float*)d_in[8];
    const float* Wfc  = (const float*)d_in[9];
    const float* bfc  = (const float*)d_in[10];
    float* out = (float*)d_out;

    const size_t need = (size_t)B_SZ * S_LEN * 64 * sizeof(unsigned int);  // 64 MB
    if (ws_size < need) return;
    unsigned int* gxu = (unsigned int*)d_ws;

    hipLaunchKernelGGL(xproj_kernel, dim3((B_SZ * S_LEN) / 64), dim3(256), 0, stream,
                       x, Wih0, bih0, bhh0, gxu);
    hipLaunchKernelGGL(lstm_scan_kernel, dim3(B_SZ), dim3(128), 0, stream,
                       gxu, Whh0, Wih1, Whh1, bih1, bhh1, Wfc, bfc, out);
}

// Round 14
// 259.145 us; speedup vs baseline: 1.7913x; 1.0002x over previous
//
#include <hip/hip_runtime.h>
#include <hip/hip_fp16.h>

#define B_SZ  512
#define S_LEN 512
#define D_IN  64
#define H_DIM 32
#define KPIPE 8                    // steps per super-step (ring depth)
#define NSUPER (S_LEN / KPIPE)     // 64

typedef _Float16 h2 __attribute__((ext_vector_type(2)));

__device__ __forceinline__ float fsig(float x) {
    float e = __builtin_amdgcn_exp2f(x * -1.44269504088896340736f);
    return __builtin_amdgcn_rcpf(1.0f + e);
}
__device__ __forceinline__ float ftanh(float x) {
    float e = __builtin_amdgcn_exp2f(x * -2.88539008177792681472f);
    return __builtin_fmaf(2.0f, __builtin_amdgcn_rcpf(1.0f + e), -1.0f);
}

#if __has_builtin(__builtin_amdgcn_fdot2)
__device__ __forceinline__ float fdot2(h2 a, h2 b, float c) {
    return __builtin_amdgcn_fdot2(a, b, c, false);   // v_dot2_f32_f16
}
#else
__device__ __forceinline__ float fdot2(h2 a, h2 b, float c) {
    return __builtin_fmaf((float)a[1], (float)b[1],
           __builtin_fmaf((float)a[0], (float)b[0], c));
}
#endif

__device__ __forceinline__ h2 u2h2(unsigned int u) { return __builtin_bit_cast(h2, u); }
__device__ __forceinline__ unsigned int pk16(float x, float y) {
    unsigned int lo = __half_as_ushort(__float2half_rn(x));
    unsigned int hi = __half_as_ushort(__float2half_rn(y));
    return lo | (hi << 16);
}

// Exchange with lane^1 on the VALU: v_mov_b32 dpp quad_perm:[1,0,3,2].
__device__ __forceinline__ float dpp_swap1(float x) {
    return __builtin_bit_cast(float, __builtin_amdgcn_mov_dpp(
        __builtin_bit_cast(int, x), 0xB1, 0xF, 0xF, false));
}

// Compiler-only memory fence (no instruction, doesn't drain vmcnt).
#define LDS_ORDER() asm volatile("" ::: "memory")
// LDS-drain + compiler fence, WITHOUT vmcnt drain.
#define LGKM_FENCE() asm volatile("s_waitcnt lgkmcnt(0)" ::: "memory")
// VMEM-drain (for the x staging loads), lgkm untouched.
#define VM_FENCE()   asm volatile("s_waitcnt vmcnt(0)" ::: "memory")

// ---------------------------------------------------------------------------
// SINGLE fused kernel: 2-layer LSTM scan + input projection + FC.
// block = 128 threads = 2 waves = ONE batch row; 512 blocks.
//   wave0 = input proj (gx = Wih0.x + b, computed in-wave from x staged one
//           super-step ahead) + layer 0, runs KPIPE=8 steps ahead into ring
//           h0buf[s&1][8][32].
//   wave1 = layer 1, consumes previous super-step's h0 block; + FC.
// One s_barrier per super-step. Pair-lane mapping (lane = 2j+p) + DPP
// combine; weights pinned in VGPRs via opaque asm.
// The former xproj kernel and the 128 MB gx HBM round-trip are GONE.
// ---------------------------------------------------------------------------
__global__ __launch_bounds__(128, 1) void lstm_scan_kernel(
    const float* __restrict__ x,
    const float* __restrict__ Wih0,
    const float* __restrict__ Whh0,
    const float* __restrict__ bih0,
    const float* __restrict__ bhh0,
    const float* __restrict__ Wih1,
    const float* __restrict__ Whh1,
    const float* __restrict__ bih1,
    const float* __restrict__ bhh1,
    const float* __restrict__ Wfc,
    const float* __restrict__ bfc,
    float* __restrict__ out)
{
    const int tid  = threadIdx.x;
    const int lane = tid & 63;
    const int j    = lane >> 1;
    const int p    = lane & 1;
    const int b    = blockIdx.x;
    const int rA   = p ? (32 + j) : j;    // gateA row: p=0 -> i_j, p=1 -> f_j
    const int rB   = rA + 64;             // gateB row: p=0 -> g_j, p=1 -> o_j

    __shared__ unsigned short h0buf[2][KPIPE][32];   // cross-wave ring
    __shared__ unsigned short h1sm[32];              // wave1-private
    __shared__ unsigned int   xbuf[2][KPIPE][32];    // wave0-private x (fp16x2)

    // gateA (i or f): sigmoid. gateB: p=0 -> tanh (g), p=1 -> sigmoid (o).
    const float sclB = p ? -1.44269504088896340736f : -2.88539008177792681472f;
    const float mulB = p ?  1.0f : 2.0f;
    const float addB = p ?  0.0f : -1.0f;

    if (tid < 64) {
        // ========== WAVE 0 : input-proj + layer 0 producer ==========
        // pinned weights: Wih0 rows (64 k -> 32 u32 each), Whh0 rows (16 each)
        unsigned int wi0A[32], wi0B[32], wh0A[16], wh0B[16];
        #pragma unroll
        for (int k4 = 0; k4 < 16; ++k4) {
            float4 v;
            v = reinterpret_cast<const float4*>(Wih0 + rA * 64)[k4];
            wi0A[2*k4+0] = pk16(v.x, v.y);  wi0A[2*k4+1] = pk16(v.z, v.w);
            v = reinterpret_cast<const float4*>(Wih0 + rB * 64)[k4];
            wi0B[2*k4+0] = pk16(v.x, v.y);  wi0B[2*k4+1] = pk16(v.z, v.w);
        }
        #pragma unroll
        for (int k4 = 0; k4 < 8; ++k4) {
            float4 v;
            v = reinterpret_cast<const float4*>(Whh0 + rA * 32)[k4];
            wh0A[2*k4+0] = pk16(v.x, v.y);  wh0A[2*k4+1] = pk16(v.z, v.w);
            v = reinterpret_cast<const float4*>(Whh0 + rB * 32)[k4];
            wh0B[2*k4+0] = pk16(v.x, v.y);  wh0B[2*k4+1] = pk16(v.z, v.w);
        }
        #pragma unroll
        for (int k = 0; k < 16; ++k)
            asm volatile("" : "+v"(wh0A[k]), "+v"(wh0B[k]),
                              "+v"(wi0A[k]), "+v"(wi0B[k]),
                              "+v"(wi0A[k+16]), "+v"(wi0B[k+16]));

        const float b0A = bih0[rA] + bhh0[rA];
        const float b0B = bih0[rB] + bhh0[rB];

        // x staging: lane owns 8 consecutive floats of the 512-float
        // super-step block: t_sub = lane>>3, k0 = (lane&7)*8.
        const float* xrow = x + (size_t)b * S_LEN * 64;
        const int tsub = lane >> 3;
        const int kq   = (lane & 7) * 4;     // u32 slot base (=k0/2)

        // preload sigma=0 synchronously
        float4 xr0 = reinterpret_cast<const float4*>(xrow + lane * 8)[0];
        float4 xr1 = reinterpret_cast<const float4*>(xrow + lane * 8 + 4)[0];
        VM_FENCE();
        {
            uint4 w;
            w.x = pk16(xr0.x, xr0.y);  w.y = pk16(xr0.z, xr0.w);
            w.z = pk16(xr1.x, xr1.y);  w.w = pk16(xr1.z, xr1.w);
            LDS_ORDER();
            *reinterpret_cast<uint4*>(&xbuf[0][tsub][kq]) = w;
            LDS_ORDER();
        }
        // issue sigma=1 loads (land by loop top)
        xr0 = reinterpret_cast<const float4*>(xrow + 512 + lane * 8)[0];
        xr1 = reinterpret_cast<const float4*>(xrow + 512 + lane * 8 + 4)[0];

        h2 h0p[16];
        #pragma unroll
        for (int k = 0; k < 16; ++k) h0p[k] = (h2){0, 0};
        float c0 = 0.f;

        // aA for t=0: gx(0) (h0(-1)=0)
        float aA, aB;
        {
            uint4 xv[8];
            LDS_ORDER();
            #pragma unroll
            for (int q = 0; q < 8; ++q)
                xv[q] = reinterpret_cast<const uint4*>(&xbuf[0][0][0])[q];
            float gA0 = b0A, gA1 = 0.f, gB0 = b0B, gB1 = 0.f;
            #pragma unroll
            for (int q = 0; q < 8; ++q) {
                gA0 = fdot2(u2h2(xv[q].x), u2h2(wi0A[4*q+0]), gA0);
                gA1 = fdot2(u2h2(xv[q].y), u2h2(wi0A[4*q+1]), gA1);
                gA0 = fdot2(u2h2(xv[q].z), u2h2(wi0A[4*q+2]), gA0);
                gA1 = fdot2(u2h2(xv[q].w), u2h2(wi0A[4*q+3]), gA1);
                gB0 = fdot2(u2h2(xv[q].x), u2h2(wi0B[4*q+0]), gB0);
                gB1 = fdot2(u2h2(xv[q].y), u2h2(wi0B[4*q+1]), gB1);
                gB0 = fdot2(u2h2(xv[q].z), u2h2(wi0B[4*q+2]), gB0);
                gB1 = fdot2(u2h2(xv[q].w), u2h2(wi0B[4*q+3]), gB1);
            }
            aA = gA0 + gA1;  aB = gB0 + gB1;
        }

        for (int s = 0; s < NSUPER; ++s) {
            // super-step top: land sigma=s+1, publish to xbuf[(s+1)&1],
            // issue loads for sigma=min(s+2,63).
            VM_FENCE();
            {
                uint4 w;
                w.x = pk16(xr0.x, xr0.y);  w.y = pk16(xr0.z, xr0.w);
                w.z = pk16(xr1.x, xr1.y);  w.w = pk16(xr1.z, xr1.w);
                LDS_ORDER();
                *reinterpret_cast<uint4*>(&xbuf[(s + 1) & 1][tsub][kq]) = w;
                LDS_ORDER();
            }
            {
                const int sn = (s + 2 < NSUPER) ? (s + 2) : (NSUPER - 1);
                xr0 = reinterpret_cast<const float4*>(xrow + sn * 512 + lane * 8)[0];
                xr1 = reinterpret_cast<const float4*>(xrow + sn * 512 + lane * 8 + 4)[0];
            }

            unsigned short (*slot)[32] = h0buf[s & 1];
            #pragma unroll
            for (int u = 0; u < KPIPE; ++u) {
                // early: broadcast-read x for step t+1 (latency hides under act)
                const unsigned int* xsrc = (u + 1 < KPIPE)
                    ? &xbuf[s & 1][u + 1][0] : &xbuf[(s + 1) & 1][0][0];
                uint4 xv[8];
                #pragma unroll
                for (int q = 0; q < 8; ++q)
                    xv[q] = reinterpret_cast<const uint4*>(xsrc)[q];

                // act chain + DPP combine + cell + h0(t)
                const float vA = fsig(aA);
                float vB;
                { float e = __builtin_amdgcn_exp2f(sclB * aB);
                  vB = __builtin_fmaf(mulB, __builtin_amdgcn_rcpf(1.0f + e), addB); }
                const float nA = dpp_swap1(vA);
                const float nB = dpp_swap1(vB);
                const float iv = p ? nA : vA;
                const float fv = p ? vA : nA;
                const float gv = p ? nB : vB;
                const float ov = p ? vB : nB;
                c0 = __builtin_fmaf(fv, c0, iv * gv);
                const float h0 = ov * ftanh(c0);

                // publish h0(t) into the ring; read back own packed copy
                LDS_ORDER();
                slot[u][j] = (unsigned short)__half_as_ushort(__float2half_rn(h0));
                LDS_ORDER();
                const uint4* hp = reinterpret_cast<const uint4*>(&slot[u][0]);
                uint4 a0 = hp[0], a1 = hp[1], a2 = hp[2], a3 = hp[3];

                // gx(t+1) dots first (xv ready; independent of h0p readback
                // -> these ~64 fdot2 cover the h0 LDS round-trip)
                float gA0 = b0A, gA1 = 0.f, gB0 = b0B, gB1 = 0.f;
                #pragma unroll
                for (int q = 0; q < 8; ++q) {
                    gA0 = fdot2(u2h2(xv[q].x), u2h2(wi0A[4*q+0]), gA0);
                    gA1 = fdot2(u2h2(xv[q].y), u2h2(wi0A[4*q+1]), gA1);
                    gA0 = fdot2(u2h2(xv[q].z), u2h2(wi0A[4*q+2]), gA0);
                    gA1 = fdot2(u2h2(xv[q].w), u2h2(wi0A[4*q+3]), gA1);
                    gB0 = fdot2(u2h2(xv[q].x), u2h2(wi0B[4*q+0]), gB0);
                    gB1 = fdot2(u2h2(xv[q].y), u2h2(wi0B[4*q+1]), gB1);
                    gB0 = fdot2(u2h2(xv[q].z), u2h2(wi0B[4*q+2]), gB0);
                    gB1 = fdot2(u2h2(xv[q].w), u2h2(wi0B[4*q+3]), gB1);
                }

                h2 h0n[16];
                h0n[ 0]=u2h2(a0.x); h0n[ 1]=u2h2(a0.y); h0n[ 2]=u2h2(a0.z); h0n[ 3]=u2h2(a0.w);
                h0n[ 4]=u2h2(a1.x); h0n[ 5]=u2h2(a1.y); h0n[ 6]=u2h2(a1.z); h0n[ 7]=u2h2(a1.w);
                h0n[ 8]=u2h2(a2.x); h0n[ 9]=u2h2(a2.y); h0n[10]=u2h2(a2.z); h0n[11]=u2h2(a2.w);
                h0n[12]=u2h2(a3.x); h0n[13]=u2h2(a3.y); h0n[14]=u2h2(a3.z); h0n[15]=u2h2(a3.w);
                #pragma unroll
                for (int k = 0; k < 16; ++k) h0p[k] = h0n[k];

                // Whh0 . h0(t)
                float zA0 = 0.f, zA1 = 0.f, zB0 = 0.f, zB1 = 0.f;
                #pragma unroll
                for (int k = 0; k < 16; k += 2) {
                    zA0 = fdot2(h0p[k],   u2h2(wh0A[k]),   zA0);
                    zA1 = fdot2(h0p[k+1], u2h2(wh0A[k+1]), zA1);
                    zB0 = fdot2(h0p[k],   u2h2(wh0B[k]),   zB0);
                    zB1 = fdot2(h0p[k+1], u2h2(wh0B[k+1]), zB1);
                }
                aA = (gA0 + gA1) + (zA0 + zA1);
                aB = (gB0 + gB1) + (zB0 + zB1);
            }
            LGKM_FENCE();
            __builtin_amdgcn_s_barrier();
        }
    } else {
        // ========== WAVE 1 : layer 1 consumer + FC (unchanged from R13) ====
        unsigned int wi1A[16], wi1B[16], wh1A[16], wh1B[16];
        #pragma unroll
        for (int k4 = 0; k4 < 8; ++k4) {
            float4 v;
            v = reinterpret_cast<const float4*>(Wih1 + rA * 32)[k4];
            wi1A[2*k4+0] = pk16(v.x, v.y);  wi1A[2*k4+1] = pk16(v.z, v.w);
            v = reinterpret_cast<const float4*>(Wih1 + rB * 32)[k4];
            wi1B[2*k4+0] = pk16(v.x, v.y);  wi1B[2*k4+1] = pk16(v.z, v.w);
            v = reinterpret_cast<const float4*>(Whh1 + rA * 32)[k4];
            wh1A[2*k4+0] = pk16(v.x, v.y);  wh1A[2*k4+1] = pk16(v.z, v.w);
            v = reinterpret_cast<const float4*>(Whh1 + rB * 32)[k4];
            wh1B[2*k4+0] = pk16(v.x, v.y);  wh1B[2*k4+1] = pk16(v.z, v.w);
        }
        #pragma unroll
        for (int k = 0; k < 16; ++k)
            asm volatile("" : "+v"(wi1A[k]), "+v"(wi1B[k]),
                              "+v"(wh1A[k]), "+v"(wh1B[k]));

        const float b1A = bih1[rA] + bhh1[rA];
        const float b1B = bih1[rB] + bhh1[rB];

        h2 h1p[16];
        #pragma unroll
        for (int k = 0; k < 16; ++k) h1p[k] = (h2){0, 0};   // h1(-1) = 0
        float c1 = 0.f;
        float h1last = 0.f;

        auto consume8 = [&](const unsigned short (*slot)[32]) {
            uint4 d0, d1, d2, d3;
            {
                const uint4* hq = reinterpret_cast<const uint4*>(&slot[0][0]);
                d0 = hq[0]; d1 = hq[1]; d2 = hq[2]; d3 = hq[3];
            }
            #pragma unroll
            for (int u = 0; u < KPIPE; ++u) {
                h2 h0q[16];
                h0q[ 0]=u2h2(d0.x); h0q[ 1]=u2h2(d0.y); h0q[ 2]=u2h2(d0.z); h0q[ 3]=u2h2(d0.w);
                h0q[ 4]=u2h2(d1.x); h0q[ 5]=u2h2(d1.y); h0q[ 6]=u2h2(d1.z); h0q[ 7]=u2h2(d1.w);
                h0q[ 8]=u2h2(d2.x); h0q[ 9]=u2h2(d2.y); h0q[10]=u2h2(d2.z); h0q[11]=u2h2(d2.w);
                h0q[12]=u2h2(d3.x); h0q[13]=u2h2(d3.y); h0q[14]=u2h2(d3.z); h0q[15]=u2h2(d3.w);
                if (u + 1 < KPIPE) {
                    const uint4* hq = reinterpret_cast<const uint4*>(&slot[u + 1][0]);
                    d0 = hq[0]; d1 = hq[1]; d2 = hq[2]; d3 = hq[3];
                }

                float qA0 = b1A, qA1 = 0.f, qB0 = b1B, qB1 = 0.f;
                #pragma unroll
                for (int k = 0; k < 16; k += 2) {
                    qA0 = fdot2(h0q[k],   u2h2(wi1A[k]),   qA0);
                    qA1 = fdot2(h0q[k+1], u2h2(wi1A[k+1]), qA1);
                    qB0 = fdot2(h0q[k],   u2h2(wi1B[k]),   qB0);
                    qB1 = fdot2(h0q[k+1], u2h2(wi1B[k+1]), qB1);
                }
                #pragma unroll
                for (int k = 0; k < 16; k += 2) {
                    qA0 = fdot2(h1p[k],   u2h2(wh1A[k]),   qA0);
                    qA1 = fdot2(h1p[k+1], u2h2(wh1A[k+1]), qA1);
                    qB0 = fdot2(h1p[k],   u2h2(wh1B[k]),   qB0);
                    qB1 = fdot2(h1p[k+1], u2h2(wh1B[k+1]), qB1);
                }
                const float qA = qA0 + qA1;
                const float qB = qB0 + qB1;

                const float wA = fsig(qA);
                float wB;
                { float e = __builtin_amdgcn_exp2f(sclB * qB);
                  wB = __builtin_fmaf(mulB, __builtin_amdgcn_rcpf(1.0f + e), addB); }
                const float mA = dpp_swap1(wA);
                const float mB = dpp_swap1(wB);
                const float iv1 = p ? mA : wA;
                const float fv1 = p ? wA : mA;
                const float gv1 = p ? mB : wB;
                const float ov1 = p ? wB : mB;
                c1 = __builtin_fmaf(fv1, c1, iv1 * gv1);
                const float h1 = ov1 * ftanh(c1);
                h1last = h1;

                LDS_ORDER();
                h1sm[j] = (unsigned short)__half_as_ushort(__float2half_rn(h1));
                LDS_ORDER();
                {
                    const uint4* hp = reinterpret_cast<const uint4*>(h1sm);
                    uint4 a0 = hp[0], a1 = hp[1], a2 = hp[2], a3 = hp[3];
                    h1p[ 0]=u2h2(a0.x); h1p[ 1]=u2h2(a0.y); h1p[ 2]=u2h2(a0.z); h1p[ 3]=u2h2(a0.w);
                    h1p[ 4]=u2h2(a1.x); h1p[ 5]=u2h2(a1.y); h1p[ 6]=u2h2(a1.z); h1p[ 7]=u2h2(a1.w);
                    h1p[ 8]=u2h2(a2.x); h1p[ 9]=u2h2(a2.y); h1p[10]=u2h2(a2.z); h1p[11]=u2h2(a2.w);
                    h1p[12]=u2h2(a3.x); h1p[13]=u2h2(a3.y); h1p[14]=u2h2(a3.z); h1p[15]=u2h2(a3.w);
                }
            }
        };

        for (int s = 0; s < NSUPER; ++s) {
            if (s > 0) consume8(h0buf[(s - 1) & 1]);
            LGKM_FENCE();
            __builtin_amdgcn_s_barrier();
        }
        consume8(h0buf[(NSUPER - 1) & 1]);

        // FC: pair lanes both hold h1[j]; mask odd lanes, 64-lane reduce
        float pFC = p ? 0.0f : h1last * Wfc[j];
        pFC += __shfl_xor(pFC, 32);
        pFC += __shfl_xor(pFC, 16);
        pFC += __shfl_xor(pFC, 8);
        pFC += __shfl_xor(pFC, 4);
        pFC += __shfl_xor(pFC, 2);
        pFC += __shfl_xor(pFC, 1);
        if (lane == 0) out[b] = pFC + bfc[0];
    }
}

extern "C" void kernel_launch(void* const* d_in, const int* in_sizes, int n_in,
                              void* d_out, int out_size, void* d_ws, size_t ws_size,
                              hipStream_t stream) {
    (void)in_sizes; (void)n_in; (void)out_size; (void)d_ws; (void)ws_size;
    const float* x    = (const float*)d_in[0];
    const float* Wih0 = (const float*)d_in[1];
    const float* Whh0 = (const float*)d_in[2];
    const float* bih0 = (const float*)d_in[3];
    const float* bhh0 = (const float*)d_in[4];
    const float* Wih1 = (const float*)d_in[5];
    const float* Whh1 = (const float*)d_in[6];
    const float* bih1 = (const float*)d_in[7];
    const float* bhh1 = (const float*)d_in[8];
    const float* Wfc  = (const float*)d_in[9];
    const float* bfc  = (const float*)d_in[10];
    float* out = (float*)d_out;

    hipLaunchKernelGGL(lstm_scan_kernel, dim3(B_SZ), dim3(128), 0, stream,
                       x, Wih0, Whh0, bih0, bhh0, Wih1, Whh1, bih1, bhh1,
                       Wfc, bfc, out);
}

// Round 15
// 197.203 us; speedup vs baseline: 2.3539x; 1.3141x over previous
//
#include <hip/hip_runtime.h>
#include <hip/hip_fp16.h>

#define B_SZ  512
#define S_LEN 512
#define D_IN  64
#define H_DIM 32
#define KPIPE 8                    // steps per super-step (ring depth)
#define NSUPER (S_LEN / KPIPE)     // 64

typedef _Float16 h2 __attribute__((ext_vector_type(2)));

__device__ __forceinline__ float fsig(float x) {
    float e = __builtin_amdgcn_exp2f(x * -1.44269504088896340736f);
    return __builtin_amdgcn_rcpf(1.0f + e);
}
__device__ __forceinline__ float ftanh(float x) {
    float e = __builtin_amdgcn_exp2f(x * -2.88539008177792681472f);
    return __builtin_fmaf(2.0f, __builtin_amdgcn_rcpf(1.0f + e), -1.0f);
}

#if __has_builtin(__builtin_amdgcn_fdot2)
__device__ __forceinline__ float fdot2(h2 a, h2 b, float c) {
    return __builtin_amdgcn_fdot2(a, b, c, false);   // v_dot2_f32_f16
}
#else
__device__ __forceinline__ float fdot2(h2 a, h2 b, float c) {
    return __builtin_fmaf((float)a[1], (float)b[1],
           __builtin_fmaf((float)a[0], (float)b[0], c));
}
#endif

__device__ __forceinline__ h2 u2h2(unsigned int u) { return __builtin_bit_cast(h2, u); }
__device__ __forceinline__ unsigned int pk16(float x, float y) {
    unsigned int lo = __half_as_ushort(__float2half_rn(x));
    unsigned int hi = __half_as_ushort(__float2half_rn(y));
    return lo | (hi << 16);
}

// Exchange with lane^1 on the VALU: v_mov_b32 dpp quad_perm:[1,0,3,2].
__device__ __forceinline__ float dpp_swap1(float x) {
    return __builtin_bit_cast(float, __builtin_amdgcn_mov_dpp(
        __builtin_bit_cast(int, x), 0xB1, 0xF, 0xF, false));
}

// Compiler-only memory fence (no instruction, doesn't drain vmcnt).
#define LDS_ORDER() asm volatile("" ::: "memory")
// LDS-drain + compiler fence, WITHOUT vmcnt drain.
#define LGKM_FENCE() asm volatile("s_waitcnt lgkmcnt(0)" ::: "memory")
// VMEM-drain (x staging loads), lgkm untouched.
#define VM_FENCE()   asm volatile("s_waitcnt vmcnt(0)" ::: "memory")

// ---------------------------------------------------------------------------
// SINGLE fused kernel, THREE-WAVE specialization. block = 192 thr = 3 waves
// = ONE batch row; 512 blocks = 1536 waves (6/CU).
//   wave2 = gx producer: stages x one super-step ahead, computes
//           gx(t)=Wih0.x(t)+b for block s+1 into ring gxbuf[(s+1)&1]
//           (fp16-pair per lane). Light (~200cyc/step) -> off critical path.
//   wave0 = layer 0 (R13-identical structure): act -> h0 ring -> Whh0 dots;
//           gx now read from gxbuf at super-step top (8 ds_read_b32).
//   wave1 = layer 1 + FC (R13-identical): consumes h0 block s-1.
// Parity: wave2 writes buf[(s+1)&1] / wave0 reads buf[s&1]; wave0 writes
// h0buf[s&1] / wave1 reads h0buf[(s-1)&1] -> all disjoint. 65 s_barriers
// per wave (1 prologue + 64), lgkmcnt-only drains (vmcnt stays in flight).
// ---------------------------------------------------------------------------
__global__ __launch_bounds__(192, 1) void lstm_scan_kernel(
    const float* __restrict__ x,
    const float* __restrict__ Wih0,
    const float* __restrict__ Whh0,
    const float* __restrict__ bih0,
    const float* __restrict__ bhh0,
    const float* __restrict__ Wih1,
    const float* __restrict__ Whh1,
    const float* __restrict__ bih1,
    const float* __restrict__ bhh1,
    const float* __restrict__ Wfc,
    const float* __restrict__ bfc,
    float* __restrict__ out)
{
    const int tid  = threadIdx.x;
    const int lane = tid & 63;
    const int j    = lane >> 1;
    const int p    = lane & 1;
    const int b    = blockIdx.x;
    const int rA   = p ? (32 + j) : j;    // gateA row: p=0 -> i_j, p=1 -> f_j
    const int rB   = rA + 64;             // gateB row: p=0 -> g_j, p=1 -> o_j

    __shared__ unsigned short h0buf[2][KPIPE][32];   // wave0 -> wave1
    __shared__ unsigned short h1sm[32];              // wave1-private
    __shared__ unsigned int   xbuf[KPIPE][32];       // wave2-private (x fp16x2)
    __shared__ unsigned int   gxbuf[2][KPIPE][64];   // wave2 -> wave0

    // gateA (i or f): sigmoid. gateB: p=0 -> tanh (g), p=1 -> sigmoid (o).
    const float sclB = p ? -1.44269504088896340736f : -2.88539008177792681472f;
    const float mulB = p ?  1.0f : 2.0f;
    const float addB = p ?  0.0f : -1.0f;

    if (tid < 64) {
        // ================= WAVE 0 : layer 0 (R13 structure) ================
        unsigned int wh0A[16], wh0B[16];
        #pragma unroll
        for (int k4 = 0; k4 < 8; ++k4) {
            float4 v;
            v = reinterpret_cast<const float4*>(Whh0 + rA * 32)[k4];
            wh0A[2*k4+0] = pk16(v.x, v.y);  wh0A[2*k4+1] = pk16(v.z, v.w);
            v = reinterpret_cast<const float4*>(Whh0 + rB * 32)[k4];
            wh0B[2*k4+0] = pk16(v.x, v.y);  wh0B[2*k4+1] = pk16(v.z, v.w);
        }
        #pragma unroll
        for (int k = 0; k < 16; ++k)
            asm volatile("" : "+v"(wh0A[k]), "+v"(wh0B[k]));

        h2 h0p[16];
        #pragma unroll
        for (int k = 0; k < 16; ++k) h0p[k] = (h2){0, 0};
        float c0 = 0.f;
        float zA = 0.f, zB = 0.f;         // Whh0.h0(t-1); 0 at t=0

        LGKM_FENCE();
        __builtin_amdgcn_s_barrier();     // prologue: gx block 0 ready

        for (int s = 0; s < NSUPER; ++s) {
            // fetch this super-step's 8 gx values (block fully written in s-1)
            unsigned int gxr[KPIPE];
            LDS_ORDER();
            #pragma unroll
            for (int u = 0; u < KPIPE; ++u) gxr[u] = gxbuf[s & 1][u][lane];
            LDS_ORDER();

            unsigned short (*slot)[32] = h0buf[s & 1];
            #pragma unroll
            for (int u = 0; u < KPIPE; ++u) {
                h2 g = u2h2(gxr[u]);
                const float aA = zA + (float)g[0];
                const float aB = zB + (float)g[1];

                // act chain + DPP combine + cell + h0(t)
                const float vA = fsig(aA);
                float vB;
                { float e = __builtin_amdgcn_exp2f(sclB * aB);
                  vB = __builtin_fmaf(mulB, __builtin_amdgcn_rcpf(1.0f + e), addB); }
                const float nA = dpp_swap1(vA);
                const float nB = dpp_swap1(vB);
                const float iv = p ? nA : vA;
                const float fv = p ? vA : nA;
                const float gv = p ? nB : vB;
                const float ov = p ? vB : nB;
                c0 = __builtin_fmaf(fv, c0, iv * gv);
                const float h0 = ov * ftanh(c0);

                // publish h0(t); read back own packed copy
                LDS_ORDER();
                slot[u][j] = (unsigned short)__half_as_ushort(__float2half_rn(h0));
                LDS_ORDER();
                {
                    const uint4* hp = reinterpret_cast<const uint4*>(&slot[u][0]);
                    uint4 a0 = hp[0], a1 = hp[1], a2 = hp[2], a3 = hp[3];
                    h0p[ 0]=u2h2(a0.x); h0p[ 1]=u2h2(a0.y); h0p[ 2]=u2h2(a0.z); h0p[ 3]=u2h2(a0.w);
                    h0p[ 4]=u2h2(a1.x); h0p[ 5]=u2h2(a1.y); h0p[ 6]=u2h2(a1.z); h0p[ 7]=u2h2(a1.w);
                    h0p[ 8]=u2h2(a2.x); h0p[ 9]=u2h2(a2.y); h0p[10]=u2h2(a2.z); h0p[11]=u2h2(a2.w);
                    h0p[12]=u2h2(a3.x); h0p[13]=u2h2(a3.y); h0p[14]=u2h2(a3.z); h0p[15]=u2h2(a3.w);
                }

                // Whh0 . h0(t) -> carried into step t+1
                float zA0 = 0.f, zA1 = 0.f, zB0 = 0.f, zB1 = 0.f;
                #pragma unroll
                for (int k = 0; k < 16; k += 2) {
                    zA0 = fdot2(h0p[k],   u2h2(wh0A[k]),   zA0);
                    zA1 = fdot2(h0p[k+1], u2h2(wh0A[k+1]), zA1);
                    zB0 = fdot2(h0p[k],   u2h2(wh0B[k]),   zB0);
                    zB1 = fdot2(h0p[k+1], u2h2(wh0B[k+1]), zB1);
                }
                zA = zA0 + zA1;  zB = zB0 + zB1;
            }
            LGKM_FENCE();
            __builtin_amdgcn_s_barrier();
        }
    } else if (tid < 128) {
        // ================= WAVE 1 : layer 1 + FC (R13-identical) ===========
        unsigned int wi1A[16], wi1B[16], wh1A[16], wh1B[16];
        #pragma unroll
        for (int k4 = 0; k4 < 8; ++k4) {
            float4 v;
            v = reinterpret_cast<const float4*>(Wih1 + rA * 32)[k4];
            wi1A[2*k4+0] = pk16(v.x, v.y);  wi1A[2*k4+1] = pk16(v.z, v.w);
            v = reinterpret_cast<const float4*>(Wih1 + rB * 32)[k4];
            wi1B[2*k4+0] = pk16(v.x, v.y);  wi1B[2*k4+1] = pk16(v.z, v.w);
            v = reinterpret_cast<const float4*>(Whh1 + rA * 32)[k4];
            wh1A[2*k4+0] = pk16(v.x, v.y);  wh1A[2*k4+1] = pk16(v.z, v.w);
            v = reinterpret_cast<const float4*>(Whh1 + rB * 32)[k4];
            wh1B[2*k4+0] = pk16(v.x, v.y);  wh1B[2*k4+1] = pk16(v.z, v.w);
        }
        #pragma unroll
        for (int k = 0; k < 16; ++k)
            asm volatile("" : "+v"(wi1A[k]), "+v"(wi1B[k]),
                              "+v"(wh1A[k]), "+v"(wh1B[k]));

        const float b1A = bih1[rA] + bhh1[rA];
        const float b1B = bih1[rB] + bhh1[rB];

        h2 h1p[16];
        #pragma unroll
        for (int k = 0; k < 16; ++k) h1p[k] = (h2){0, 0};   // h1(-1) = 0
        float c1 = 0.f;
        float h1last = 0.f;

        auto consume8 = [&](const unsigned short (*slot)[32]) {
            uint4 d0, d1, d2, d3;
            {
                const uint4* hq = reinterpret_cast<const uint4*>(&slot[0][0]);
                d0 = hq[0]; d1 = hq[1]; d2 = hq[2]; d3 = hq[3];
            }
            #pragma unroll
            for (int u = 0; u < KPIPE; ++u) {
                h2 h0q[16];
                h0q[ 0]=u2h2(d0.x); h0q[ 1]=u2h2(d0.y); h0q[ 2]=u2h2(d0.z); h0q[ 3]=u2h2(d0.w);
                h0q[ 4]=u2h2(d1.x); h0q[ 5]=u2h2(d1.y); h0q[ 6]=u2h2(d1.z); h0q[ 7]=u2h2(d1.w);
                h0q[ 8]=u2h2(d2.x); h0q[ 9]=u2h2(d2.y); h0q[10]=u2h2(d2.z); h0q[11]=u2h2(d2.w);
                h0q[12]=u2h2(d3.x); h0q[13]=u2h2(d3.y); h0q[14]=u2h2(d3.z); h0q[15]=u2h2(d3.w);
                if (u + 1 < KPIPE) {
                    const uint4* hq = reinterpret_cast<const uint4*>(&slot[u + 1][0]);
                    d0 = hq[0]; d1 = hq[1]; d2 = hq[2]; d3 = hq[3];
                }

                float qA0 = b1A, qA1 = 0.f, qB0 = b1B, qB1 = 0.f;
                #pragma unroll
                for (int k = 0; k < 16; k += 2) {
                    qA0 = fdot2(h0q[k],   u2h2(wi1A[k]),   qA0);
                    qA1 = fdot2(h0q[k+1], u2h2(wi1A[k+1]), qA1);
                    qB0 = fdot2(h0q[k],   u2h2(wi1B[k]),   qB0);
                    qB1 = fdot2(h0q[k+1], u2h2(wi1B[k+1]), qB1);
                }
                #pragma unroll
                for (int k = 0; k < 16; k += 2) {
                    qA0 = fdot2(h1p[k],   u2h2(wh1A[k]),   qA0);
                    qA1 = fdot2(h1p[k+1], u2h2(wh1A[k+1]), qA1);
                    qB0 = fdot2(h1p[k],   u2h2(wh1B[k]),   qB0);
                    qB1 = fdot2(h1p[k+1], u2h2(wh1B[k+1]), qB1);
                }
                const float qA = qA0 + qA1;
                const float qB = qB0 + qB1;

                const float wA = fsig(qA);
                float wB;
                { float e = __builtin_amdgcn_exp2f(sclB * qB);
                  wB = __builtin_fmaf(mulB, __builtin_amdgcn_rcpf(1.0f + e), addB); }
                const float mA = dpp_swap1(wA);
                const float mB = dpp_swap1(wB);
                const float iv1 = p ? mA : wA;
                const float fv1 = p ? wA : mA;
                const float gv1 = p ? mB : wB;
                const float ov1 = p ? wB : mB;
                c1 = __builtin_fmaf(fv1, c1, iv1 * gv1);
                const float h1 = ov1 * ftanh(c1);
                h1last = h1;

                LDS_ORDER();
                h1sm[j] = (unsigned short)__half_as_ushort(__float2half_rn(h1));
                LDS_ORDER();
                {
                    const uint4* hp = reinterpret_cast<const uint4*>(h1sm);
                    uint4 a0 = hp[0], a1 = hp[1], a2 = hp[2], a3 = hp[3];
                    h1p[ 0]=u2h2(a0.x); h1p[ 1]=u2h2(a0.y); h1p[ 2]=u2h2(a0.z); h1p[ 3]=u2h2(a0.w);
                    h1p[ 4]=u2h2(a1.x); h1p[ 5]=u2h2(a1.y); h1p[ 6]=u2h2(a1.z); h1p[ 7]=u2h2(a1.w);
                    h1p[ 8]=u2h2(a2.x); h1p[ 9]=u2h2(a2.y); h1p[10]=u2h2(a2.z); h1p[11]=u2h2(a2.w);
                    h1p[12]=u2h2(a3.x); h1p[13]=u2h2(a3.y); h1p[14]=u2h2(a3.z); h1p[15]=u2h2(a3.w);
                }
            }
        };

        LGKM_FENCE();
        __builtin_amdgcn_s_barrier();     // prologue
        for (int s = 0; s < NSUPER; ++s) {
            if (s > 0) consume8(h0buf[(s - 1) & 1]);
            LGKM_FENCE();
            __builtin_amdgcn_s_barrier();
        }
        consume8(h0buf[(NSUPER - 1) & 1]);

        // FC: pair lanes both hold h1[j]; mask odd lanes, 64-lane reduce
        float pFC = p ? 0.0f : h1last * Wfc[j];
        pFC += __shfl_xor(pFC, 32);
        pFC += __shfl_xor(pFC, 16);
        pFC += __shfl_xor(pFC, 8);
        pFC += __shfl_xor(pFC, 4);
        pFC += __shfl_xor(pFC, 2);
        pFC += __shfl_xor(pFC, 1);
        if (lane == 0) out[b] = pFC + bfc[0];
    } else {
        // ================= WAVE 2 : gx producer ============================
        unsigned int wi0A[32], wi0B[32];
        #pragma unroll
        for (int k4 = 0; k4 < 16; ++k4) {
            float4 v;
            v = reinterpret_cast<const float4*>(Wih0 + rA * 64)[k4];
            wi0A[2*k4+0] = pk16(v.x, v.y);  wi0A[2*k4+1] = pk16(v.z, v.w);
            v = reinterpret_cast<const float4*>(Wih0 + rB * 64)[k4];
            wi0B[2*k4+0] = pk16(v.x, v.y);  wi0B[2*k4+1] = pk16(v.z, v.w);
        }
        #pragma unroll
        for (int k = 0; k < 32; ++k)
            asm volatile("" : "+v"(wi0A[k]), "+v"(wi0B[k]));

        const float b0A = bih0[rA] + bhh0[rA];
        const float b0B = bih0[rB] + bhh0[rB];

        // x staging: lane owns 8 consecutive floats of each 512-float block.
        const float* xrow = x + (size_t)b * S_LEN * 64;
        const int tsub = lane >> 3;
        const int kq   = (lane & 7) * 4;

        auto stage = [&](float4 xr0, float4 xr1) {
            uint4 w;
            w.x = pk16(xr0.x, xr0.y);  w.y = pk16(xr0.z, xr0.w);
            w.z = pk16(xr1.x, xr1.y);  w.w = pk16(xr1.z, xr1.w);
            LDS_ORDER();
            *reinterpret_cast<uint4*>(&xbuf[tsub][kq]) = w;
            LDS_ORDER();
        };
        auto compute_block = [&](unsigned int (*dst)[64]) {
            #pragma unroll
            for (int u = 0; u < KPIPE; ++u) {
                uint4 xv[8];
                #pragma unroll
                for (int q = 0; q < 8; ++q)
                    xv[q] = reinterpret_cast<const uint4*>(&xbuf[u][0])[q];
                float gA0 = b0A, gA1 = 0.f, gB0 = b0B, gB1 = 0.f;
                #pragma unroll
                for (int q = 0; q < 8; ++q) {
                    gA0 = fdot2(u2h2(xv[q].x), u2h2(wi0A[4*q+0]), gA0);
                    gA1 = fdot2(u2h2(xv[q].y), u2h2(wi0A[4*q+1]), gA1);
                    gA0 = fdot2(u2h2(xv[q].z), u2h2(wi0A[4*q+2]), gA0);
                    gA1 = fdot2(u2h2(xv[q].w), u2h2(wi0A[4*q+3]), gA1);
                    gB0 = fdot2(u2h2(xv[q].x), u2h2(wi0B[4*q+0]), gB0);
                    gB1 = fdot2(u2h2(xv[q].y), u2h2(wi0B[4*q+1]), gB1);
                    gB0 = fdot2(u2h2(xv[q].z), u2h2(wi0B[4*q+2]), gB0);
                    gB1 = fdot2(u2h2(xv[q].w), u2h2(wi0B[4*q+3]), gB1);
                }
                LDS_ORDER();
                dst[u][lane] = pk16(gA0 + gA1, gB0 + gB1);
                LDS_ORDER();
            }
        };

        // prologue: block 0 sync -> gxbuf[0]; issue block 1 loads
        float4 xr0 = reinterpret_cast<const float4*>(xrow + lane * 8)[0];
        float4 xr1 = reinterpret_cast<const float4*>(xrow + lane * 8 + 4)[0];
        VM_FENCE();
        stage(xr0, xr1);
        compute_block(gxbuf[0]);
        xr0 = reinterpret_cast<const float4*>(xrow + 512 + lane * 8)[0];
        xr1 = reinterpret_cast<const float4*>(xrow + 512 + lane * 8 + 4)[0];

        LGKM_FENCE();
        __builtin_amdgcn_s_barrier();     // prologue

        for (int s = 0; s < NSUPER; ++s) {
            VM_FENCE();                   // block min(s+1,63) landed
            stage(xr0, xr1);
            compute_block(gxbuf[(s + 1) & 1]);
            const int sn = (s + 2 < NSUPER) ? (s + 2) : (NSUPER - 1);
            xr0 = reinterpret_cast<const float4*>(xrow + sn * 512 + lane * 8)[0];
            xr1 = reinterpret_cast<const float4*>(xrow + sn * 512 + lane * 8 + 4)[0];
            LGKM_FENCE();
            __builtin_amdgcn_s_barrier();
        }
    }
}

extern "C" void kernel_launch(void* const* d_in, const int* in_sizes, int n_in,
                              void* d_out, int out_size, void* d_ws, size_t ws_size,
                              hipStream_t stream) {
    (void)in_sizes; (void)n_in; (void)out_size; (void)d_ws; (void)ws_size;
    const float* x    = (const float*)d_in[0];
    const float* Wih0 = (const float*)d_in[1];
    const float* Whh0 = (const float*)d_in[2];
    const float* bih0 = (const float*)d_in[3];
    const float* bhh0 = (const float*)d_in[4];
    const float* Wih1 = (const float*)d_in[5];
    const float* Whh1 = (const float*)d_in[6];
    const float* bih1 = (const float*)d_in[7];
    const float* bhh1 = (const float*)d_in[8];
    const float* Wfc  = (const float*)d_in[9];
    const float* bfc  = (const float*)d_in[10];
    float* out = (float*)d_out;

    hipLaunchKernelGGL(lstm_scan_kernel, dim3(B_SZ), dim3(192), 0, stream,
                       x, Wih0, Whh0, bih0, bhh0, Wih1, Whh1, bih1, bhh1,
                       Wfc, bfc, out);
}